// Round 8
// baseline (205.120 us; speedup 1.0000x reference)
//
#include <hip/hip_runtime.h>
#include <hip/hip_bf16.h>

typedef float v4f __attribute__((ext_vector_type(4)));
typedef short v4s __attribute__((ext_vector_type(4)));
typedef short bfrag8 __attribute__((ext_vector_type(8)));

// Problem constants (match reference)
constexpr int NXc = 100, NYc = 100, NZc = 10;
constexpr int NVOX = NZc * NYc * NXc;      // 100000
constexpr int CO = 256, CG = 48;
constexpr int BT = 2;
constexpr int NPT = 6 * 32 * 88;           // 16896 points per bt
constexpr int NPTS = BT * NPT;             // 33792
constexpr int MAXS = NPTS;                 // max occupied voxels
constexpr int NPAIR = NVOX / 32;           // 3125 32-vox pairs per bt
constexpr float GMX = -40.0f, GMY = -40.0f, GMZ = -2.0f;
constexpr float VOXEL = 0.8f;

static __device__ __forceinline__ short f2bf(float f) {
    __hip_bfloat16 h = __float2bfloat16(f);
    return __builtin_bit_cast(short, h);
}
static __device__ __forceinline__ float bf2f(unsigned short u) {
    unsigned v = (unsigned)u << 16;
    return __builtin_bit_cast(float, v);
}

// ---------------------------------------------------------------------------
// Pass 0: blocks 0..1023 zero the scatter scratch; block 1024 packs Wo2g^T
// into bf16 MFMA A-fragments: lane l slot j holds W[k][g],
// k = s*32 + (l>>4)*8 + j, g = gt*16 + (l&15); wp[((s*3+gt)*64 + l)*8 + j].
// ---------------------------------------------------------------------------
__global__ __launch_bounds__(256) void k_init(
    v4f* __restrict__ p, int n16,
    const float* __restrict__ Wo2g, short* __restrict__ wp)
{
    if (blockIdx.x < 1024) {
        v4f z = {0.f, 0.f, 0.f, 0.f};
        for (int i = blockIdx.x * 256 + threadIdx.x; i < n16; i += 1024 * 256)
            p[i] = z;
    } else {
        for (int e = threadIdx.x; e < 8 * 3 * 64 * 8; e += 256) {
            int j  = e & 7;
            int l  = (e >> 3) & 63;
            int ft = e >> 9;                      // s*3 + gt
            int s  = ft / 3, gt = ft - 3 * s;
            int k  = s * 32 + (l >> 4) * 8 + j;
            int g  = gt * 16 + (l & 15);
            wp[e] = f2bf(Wo2g[k * CG + g]);
        }
    }
}

// ---------------------------------------------------------------------------
// Pass 1: per point -> voxel; count + assign compact slots + slot list.
// ---------------------------------------------------------------------------
__global__ __launch_bounds__(256) void k_count(
    const float* __restrict__ pts, float* __restrict__ cnt,
    int* __restrict__ nocc, int* __restrict__ invmap, int* __restrict__ ptvox,
    int* __restrict__ list)
{
    int pn = blockIdx.x * 256 + threadIdx.x;      // < NPTS (exact grid)
    float x = pts[pn * 3 + 0];
    float y = pts[pn * 3 + 1];
    float z = pts[pn * 3 + 2];
    int ix = (int)floorf((x - GMX) / VOXEL);
    int iy = (int)floorf((y - GMY) / VOXEL);
    int iz = (int)floorf((z - GMZ) / VOXEL);
    bool valid = (ix >= 0 && ix < NXc && iy >= 0 && iy < NYc && iz >= 0 && iz < NZc);
    if (!valid) { ptvox[pn] = -1; return; }
    int bt = pn / NPT;
    int btvox = bt * NVOX + iz * (NYc * NXc) + iy * NXc + ix;
    ptvox[pn] = btvox;
    float old = atomicAdd(&cnt[btvox], 1.0f);
    if (old == 0.0f) {
        int s = atomicAdd(nocc, 1);
        invmap[btvox] = s + 1;                    // 0 = empty
        list[s] = btvox;
    }
}

// ---------------------------------------------------------------------------
// Pass 2: scatter-add 48-dim features into compact mean buffer.
// ---------------------------------------------------------------------------
__global__ __launch_bounds__(256) void k_scatterM(
    const float* __restrict__ feats, const int* __restrict__ ptvox,
    const int* __restrict__ invmap, float* __restrict__ compactM)
{
    int idx = blockIdx.x * 256 + threadIdx.x;     // (pn)*CG + k, < NPTS*CG
    int k  = idx % CG;
    int pn = idx / CG;
    int bv = ptvox[pn];
    if (bv < 0) return;
    int slot = invmap[bv] - 1;
    atomicAdd(&compactM[(size_t)slot * CG + k], feats[idx]);
}

// ---------------------------------------------------------------------------
// Pass 3: P[bt][vox][48] (bf16) = occ[bt][:,vox]^T @ Wo2g via bf16 MFMA.
// One wave per 32-vox pair (2 tiles). W fragments register-hoisted.
// C/D layout (m89): col = lane&15 (vox), row = (lane>>4)*4+reg (g).
// ---------------------------------------------------------------------------
__global__ __launch_bounds__(256) void k_volproj(
    const float* __restrict__ occ, const short* __restrict__ wp,
    unsigned short* __restrict__ P)
{
    int gwid = (blockIdx.x * 256 + threadIdx.x) >> 6;
    if (gwid >= BT * NPAIR) return;
    int l = threadIdx.x & 63;
    int q = l >> 4, r = l & 15;
    const bfrag8* wf = reinterpret_cast<const bfrag8*>(wp);
    bfrag8 wfr[8][3];
#pragma unroll
    for (int s = 0; s < 8; ++s)
#pragma unroll
        for (int gt = 0; gt < 3; ++gt)
            wfr[s][gt] = wf[(s * 3 + gt) * 64 + l];
    int bt = gwid / NPAIR;
    int vox0 = (gwid - bt * NPAIR) * 32;
    const float* b0 = occ + (size_t)bt * CO * NVOX + (size_t)q * 8 * NVOX + vox0 + r;
    v4f acc0[3] = {{0.f,0.f,0.f,0.f},{0.f,0.f,0.f,0.f},{0.f,0.f,0.f,0.f}};
    v4f acc1[3] = {{0.f,0.f,0.f,0.f},{0.f,0.f,0.f,0.f},{0.f,0.f,0.f,0.f}};
#pragma unroll
    for (int s = 0; s < 8; ++s) {
        float t0[8], t1[8];
#pragma unroll
        for (int j = 0; j < 8; ++j) {
            const float* a = b0 + (size_t)(s * 32 + j) * NVOX;
            t0[j] = a[0];
            t1[j] = a[16];
        }
        bfrag8 bf0, bf1;
#pragma unroll
        for (int j = 0; j < 8; ++j) { bf0[j] = f2bf(t0[j]); bf1[j] = f2bf(t1[j]); }
#pragma unroll
        for (int gt = 0; gt < 3; ++gt) {
            acc0[gt] = __builtin_amdgcn_mfma_f32_16x16x32_bf16(wfr[s][gt], bf0, acc0[gt], 0, 0, 0);
            acc1[gt] = __builtin_amdgcn_mfma_f32_16x16x32_bf16(wfr[s][gt], bf1, acc1[gt], 0, 0, 0);
        }
    }
    unsigned short* o0 = P + ((size_t)bt * NVOX + vox0 + r) * CG + q * 4;
    unsigned short* o1 = o0 + (size_t)16 * CG;
#pragma unroll
    for (int gt = 0; gt < 3; ++gt) {
        v4s s0, s1;
#pragma unroll
        for (int e = 0; e < 4; ++e) { s0[e] = f2bf(acc0[gt][e]); s1[e] = f2bf(acc1[gt][e]); }
        *reinterpret_cast<v4s*>(o0 + 16 * gt) = s0;
        *reinterpret_cast<v4s*>(o1 + 16 * gt) = s1;
    }
}

// ---------------------------------------------------------------------------
// Pass 4: trilinear gather from bf16 P + bias -> occ_to_gs output (f32).
// ---------------------------------------------------------------------------
__global__ __launch_bounds__(256) void k_gather(
    const float* __restrict__ pts, const unsigned short* __restrict__ P,
    const float* __restrict__ bo2g, float* __restrict__ out1)
{
    int idx = blockIdx.x * 256 + threadIdx.x;     // (pn)*CG + g
    int g  = idx % CG;
    int pn = idx / CG;
    int bt = pn / NPT;
    float x = pts[pn * 3 + 0];
    float y = pts[pn * 3 + 1];
    float z = pts[pn * 3 + 2];
    float gx = (x - GMX) / 80.0f * 2.0f - 1.0f;
    float gy = (y - GMY) / 80.0f * 2.0f - 1.0f;
    float gz = (z - GMZ) / 8.0f  * 2.0f - 1.0f;
    float px = ((gx + 1.0f) * (float)NXc - 1.0f) * 0.5f;
    float py = ((gy + 1.0f) * (float)NYc - 1.0f) * 0.5f;
    float pz = ((gz + 1.0f) * (float)NZc - 1.0f) * 0.5f;
    float fx = floorf(px), fy = floorf(py), fz = floorf(pz);
    float rx = px - fx, ry = py - fy, rz = pz - fz;
    int x0 = (int)fx, y0 = (int)fy, z0 = (int)fz;
    float acc = bo2g[g];
    const unsigned short* Pb = P + (size_t)bt * NVOX * CG;
#pragma unroll
    for (int dz = 0; dz <= 1; ++dz) {
        int zi = z0 + dz;
        if (zi < 0 || zi >= NZc) continue;
        float wz = dz ? rz : 1.0f - rz;
#pragma unroll
        for (int dy = 0; dy <= 1; ++dy) {
            int yi = y0 + dy;
            if (yi < 0 || yi >= NYc) continue;
            float wy = dy ? ry : 1.0f - ry;
#pragma unroll
            for (int dx = 0; dx <= 1; ++dx) {
                int xi = x0 + dx;
                if (xi < 0 || xi >= NXc) continue;
                float wx = dx ? rx : 1.0f - rx;
                float w = (wx * wy) * wz;
                int lin = zi * (NYc * NXc) + yi * NXc + xi;
                acc = fmaf(w, bf2f(Pb[(size_t)lin * CG + g]), acc);
            }
        }
    }
    out1[idx] = acc;
}

// ---------------------------------------------------------------------------
// Pass 5: sparse GEMM — compact256h[slot][256] (bf16) = mean[48] @ Wg2o + b.
// ---------------------------------------------------------------------------
__global__ __launch_bounds__(256) void k_gemm(
    const float* __restrict__ compactM, const float* __restrict__ cnt,
    const int* __restrict__ list, const int* __restrict__ noccp,
    const float* __restrict__ Wg2o, const float* __restrict__ bg2o,
    unsigned short* __restrict__ compact256h)
{
    int nocc = *noccp;
    int s0 = blockIdx.x * 32;
    if (s0 >= nocc) return;                      // uniform per block
    __shared__ float Wl[CG * CO];                // 48 KB, [k][c]
    __shared__ float Ml[32 * CG];                // 6 KB means
    for (int j = threadIdx.x; j < CG * CO; j += 256) Wl[j] = Wg2o[j];
    for (int j = threadIdx.x; j < 32 * CG; j += 256) {
        int v = j / CG, k = j - v * CG;
        int slot = s0 + v;
        float m = 0.f;
        if (slot < nocc) {
            int btvox = list[slot];
            m = compactM[(size_t)slot * CG + k] / cnt[btvox];
        }
        Ml[j] = m;
    }
    __syncthreads();
    int wid = threadIdx.x >> 6, l = threadIdx.x & 63;
    int vb = wid * 8;
    float4 bias = *reinterpret_cast<const float4*>(&bg2o[4 * l]);
    float acc[8][4];
#pragma unroll
    for (int v = 0; v < 8; ++v) {
        acc[v][0] = bias.x; acc[v][1] = bias.y; acc[v][2] = bias.z; acc[v][3] = bias.w;
    }
    for (int k = 0; k < CG; k += 4) {
        float4 w0 = *reinterpret_cast<const float4*>(&Wl[(k + 0) * CO + 4 * l]);
        float4 w1 = *reinterpret_cast<const float4*>(&Wl[(k + 1) * CO + 4 * l]);
        float4 w2 = *reinterpret_cast<const float4*>(&Wl[(k + 2) * CO + 4 * l]);
        float4 w3 = *reinterpret_cast<const float4*>(&Wl[(k + 3) * CO + 4 * l]);
#pragma unroll
        for (int v = 0; v < 8; ++v) {
            float4 m4 = *reinterpret_cast<const float4*>(&Ml[(vb + v) * CG + k]);
            acc[v][0] = fmaf(m4.x, w0.x, acc[v][0]);
            acc[v][1] = fmaf(m4.x, w0.y, acc[v][1]);
            acc[v][2] = fmaf(m4.x, w0.z, acc[v][2]);
            acc[v][3] = fmaf(m4.x, w0.w, acc[v][3]);
            acc[v][0] = fmaf(m4.y, w1.x, acc[v][0]);
            acc[v][1] = fmaf(m4.y, w1.y, acc[v][1]);
            acc[v][2] = fmaf(m4.y, w1.z, acc[v][2]);
            acc[v][3] = fmaf(m4.y, w1.w, acc[v][3]);
            acc[v][0] = fmaf(m4.z, w2.x, acc[v][0]);
            acc[v][1] = fmaf(m4.z, w2.y, acc[v][1]);
            acc[v][2] = fmaf(m4.z, w2.z, acc[v][2]);
            acc[v][3] = fmaf(m4.z, w2.w, acc[v][3]);
            acc[v][0] = fmaf(m4.w, w3.x, acc[v][0]);
            acc[v][1] = fmaf(m4.w, w3.y, acc[v][1]);
            acc[v][2] = fmaf(m4.w, w3.z, acc[v][2]);
            acc[v][3] = fmaf(m4.w, w3.w, acc[v][3]);
        }
    }
#pragma unroll
    for (int v = 0; v < 8; ++v) {
        int slot = s0 + vb + v;
        if (slot < nocc) {
            v4s rr;
#pragma unroll
            for (int e = 0; e < 4; ++e) rr[e] = f2bf(acc[v][e]);
            *reinterpret_cast<v4s*>(&compact256h[(size_t)slot * CO + 4 * l]) = rr;
        }
    }
}

// ---------------------------------------------------------------------------
// Pass 6: dense writer. Thread -> 4 consecutive vox; loop 32 channels.
// Reads bf16 compact rows (L1-reused lines), writes f32 out0.
// ---------------------------------------------------------------------------
__global__ __launch_bounds__(256) void k_writer(
    const int* __restrict__ invmap, const unsigned short* __restrict__ compact256h,
    float* __restrict__ out0)
{
    int bt = blockIdx.z;
    int c0 = blockIdx.y * 32;
    int v0 = blockIdx.x * 1024 + threadIdx.x * 4;
    if (v0 >= NVOX) return;
    int4 sp = *reinterpret_cast<const int4*>(&invmap[bt * NVOX + v0]);
    const unsigned short* r0 = compact256h + (size_t)(sp.x - 1) * CO;
    const unsigned short* r1 = compact256h + (size_t)(sp.y - 1) * CO;
    const unsigned short* r2 = compact256h + (size_t)(sp.z - 1) * CO;
    const unsigned short* r3 = compact256h + (size_t)(sp.w - 1) * CO;
    float* ob = out0 + (size_t)bt * CO * NVOX + (size_t)c0 * NVOX + v0;
#pragma unroll 4
    for (int ci = 0; ci < 32; ++ci) {
        int c = c0 + ci;
        v4f val;
        val.x = sp.x ? bf2f(r0[c]) : 0.f;
        val.y = sp.y ? bf2f(r1[c]) : 0.f;
        val.z = sp.z ? bf2f(r2[c]) : 0.f;
        val.w = sp.w ? bf2f(r3[c]) : 0.f;
        __builtin_nontemporal_store(val, reinterpret_cast<v4f*>(ob + (size_t)ci * NVOX));
    }
}

// ---------------------------------------------------------------------------
extern "C" void kernel_launch(void* const* d_in, const int* in_sizes, int n_in,
                              void* d_out, int out_size, void* d_ws, size_t ws_size,
                              hipStream_t stream)
{
    const float* centers = (const float*)d_in[0];
    const float* feats   = (const float*)d_in[1];
    const float* occ     = (const float*)d_in[2];
    const float* Wg2o    = (const float*)d_in[3];
    const float* bg2o    = (const float*)d_in[4];
    const float* Wo2g    = (const float*)d_in[5];
    const float* bo2g    = (const float*)d_in[6];

    float* out  = (float*)d_out;
    float* out0 = out;                                   // [BT][CO][NVOX]
    float* out1 = out + (size_t)BT * CO * NVOX;          // [BT][NPT][CG]
    // bf16 P in tail of out0: written by volproj, read by gather, overwritten
    // by writer (stream-ordered).
    unsigned short* P = (unsigned short*)((char*)out0 + (size_t)BT * CO * NVOX * 4
                                          - (size_t)BT * NVOX * CG * 2);
    // Packed bf16 W fragments at head of out1 (24 KB): written by k_init,
    // read by k_volproj, then fully overwritten by k_gather.
    short* wp   = (short*)out1;

    // ws layout: zeroed region first (cnt, nocc, invmap, compactM), then rest.
    char* w = (char*)d_ws;
    float* cnt       = (float*)w;                 w += (size_t)BT * NVOX * 4;       // 800000
    int*   nocc      = (int*)w;                   w += 256;
    int*   invmap    = (int*)w;                   w += (size_t)BT * NVOX * 4;       // 800000
    float* compactM  = (float*)w;                 w += (size_t)MAXS * CG * 4;       // 6488064
    size_t zbytes = (size_t)BT * NVOX * 4 + 256 + (size_t)BT * NVOX * 4
                  + (size_t)MAXS * CG * 4;       // 8,088,320 (16B-divisible)
    int*   ptvox     = (int*)w;                   w += (size_t)NPTS * 4;            // 135168
    int*   list      = (int*)w;                   w += (size_t)MAXS * 4;            // 135168
    unsigned short* compact256h = (unsigned short*)w;    // MAXS*CO*2 = 17301504

    k_init<<<1025, 256, 0, stream>>>((v4f*)d_ws, (int)(zbytes / 16), Wo2g, wp);
    k_count<<<NPTS / 256, 256, 0, stream>>>(centers, cnt, nocc, invmap, ptvox, list);
    k_scatterM<<<NPTS * CG / 256, 256, 0, stream>>>(feats, ptvox, invmap, compactM);
    k_volproj<<<(BT * NPAIR + 3) / 4, 256, 0, stream>>>(occ, wp, P);
    k_gather<<<NPTS * CG / 256, 256, 0, stream>>>(centers, P, bo2g, out1);
    k_gemm<<<(MAXS + 31) / 32, 256, 0, stream>>>(compactM, cnt, list, nocc, Wg2o, bg2o, compact256h);
    k_writer<<<dim3((NVOX + 1023) / 1024, 8, BT), 256, 0, stream>>>(invmap, compact256h, out0);
}

// Round 9
// 177.572 us; speedup vs baseline: 1.1551x; 1.1551x over previous
//
#include <hip/hip_runtime.h>
#include <hip/hip_bf16.h>

typedef float v4f __attribute__((ext_vector_type(4)));
typedef short bfrag8 __attribute__((ext_vector_type(8)));

// Problem constants (match reference)
constexpr int NXc = 100, NYc = 100, NZc = 10;
constexpr int NVOX = NZc * NYc * NXc;      // 100000
constexpr int CO = 256, CG = 48;
constexpr int BT = 2;
constexpr int NPT = 6 * 32 * 88;           // 16896 points per bt
constexpr int NPTS = BT * NPT;             // 33792
constexpr int MAXS = NPTS;                 // max occupied voxels
constexpr int NPAIR = NVOX / 32;           // 3125 32-vox pairs per bt
constexpr float GMX = -40.0f, GMY = -40.0f, GMZ = -2.0f;
constexpr float VOXEL = 0.8f;

static __device__ __forceinline__ short f2bf(float f) {
    __hip_bfloat16 h = __float2bfloat16(f);
    return __builtin_bit_cast(short, h);
}

// ---------------------------------------------------------------------------
// Pass 0: blocks 0..1023 zero the scatter scratch; block 1024 packs Wo2g^T
// into bf16 MFMA A-fragments: lane l slot j holds W[k][g],
// k = s*32 + (l>>4)*8 + j, g = gt*16 + (l&15); wp[((s*3+gt)*64 + l)*8 + j].
// ---------------------------------------------------------------------------
__global__ __launch_bounds__(256) void k_init(
    v4f* __restrict__ p, int n16,
    const float* __restrict__ Wo2g, short* __restrict__ wp)
{
    if (blockIdx.x < 1024) {
        v4f z = {0.f, 0.f, 0.f, 0.f};
        for (int i = blockIdx.x * 256 + threadIdx.x; i < n16; i += 1024 * 256)
            p[i] = z;
    } else {
        for (int e = threadIdx.x; e < 8 * 3 * 64 * 8; e += 256) {
            int j  = e & 7;
            int l  = (e >> 3) & 63;
            int ft = e >> 9;                      // s*3 + gt
            int s  = ft / 3, gt = ft - 3 * s;
            int k  = s * 32 + (l >> 4) * 8 + j;
            int g  = gt * 16 + (l & 15);
            wp[e] = f2bf(Wo2g[k * CG + g]);
        }
    }
}

// ---------------------------------------------------------------------------
// Pass 1: per point -> voxel; count + assign compact slots + slot list.
// ---------------------------------------------------------------------------
__global__ __launch_bounds__(256) void k_count(
    const float* __restrict__ pts, float* __restrict__ cnt,
    int* __restrict__ nocc, int* __restrict__ invmap, int* __restrict__ ptvox,
    int* __restrict__ list)
{
    int pn = blockIdx.x * 256 + threadIdx.x;      // < NPTS (exact grid)
    float x = pts[pn * 3 + 0];
    float y = pts[pn * 3 + 1];
    float z = pts[pn * 3 + 2];
    int ix = (int)floorf((x - GMX) / VOXEL);
    int iy = (int)floorf((y - GMY) / VOXEL);
    int iz = (int)floorf((z - GMZ) / VOXEL);
    bool valid = (ix >= 0 && ix < NXc && iy >= 0 && iy < NYc && iz >= 0 && iz < NZc);
    if (!valid) { ptvox[pn] = -1; return; }
    int bt = pn / NPT;
    int btvox = bt * NVOX + iz * (NYc * NXc) + iy * NXc + ix;
    ptvox[pn] = btvox;
    float old = atomicAdd(&cnt[btvox], 1.0f);
    if (old == 0.0f) {
        int s = atomicAdd(nocc, 1);
        invmap[btvox] = s + 1;                    // 0 = empty
        list[s] = btvox;
    }
}

// ---------------------------------------------------------------------------
// Pass 2: scatter-add 48-dim features into compact mean buffer.
// ---------------------------------------------------------------------------
__global__ __launch_bounds__(256) void k_scatterM(
    const float* __restrict__ feats, const int* __restrict__ ptvox,
    const int* __restrict__ invmap, float* __restrict__ compactM)
{
    int idx = blockIdx.x * 256 + threadIdx.x;     // (pn)*CG + k, < NPTS*CG
    int k  = idx % CG;
    int pn = idx / CG;
    int bv = ptvox[pn];
    if (bv < 0) return;
    int slot = invmap[bv] - 1;
    atomicAdd(&compactM[(size_t)slot * CG + k], feats[idx]);
}

// ---------------------------------------------------------------------------
// Pass 3: P[bt][vox][48] (f32) = occ[bt][:,vox]^T @ Wo2g via bf16 MFMA.
// One wave per 32-vox pair (2 tiles). W fragments register-hoisted.
// occ is read nontemporal (205 MB read-once; keep L2 for P).
// C/D layout (m89): col = lane&15 (vox), row = (lane>>4)*4+reg (g).
// ---------------------------------------------------------------------------
__global__ __launch_bounds__(256) void k_volproj(
    const float* __restrict__ occ, const short* __restrict__ wp,
    float* __restrict__ P)
{
    int gwid = (blockIdx.x * 256 + threadIdx.x) >> 6;
    if (gwid >= BT * NPAIR) return;
    int l = threadIdx.x & 63;
    int q = l >> 4, r = l & 15;
    const bfrag8* wf = reinterpret_cast<const bfrag8*>(wp);
    bfrag8 wfr[8][3];
#pragma unroll
    for (int s = 0; s < 8; ++s)
#pragma unroll
        for (int gt = 0; gt < 3; ++gt)
            wfr[s][gt] = wf[(s * 3 + gt) * 64 + l];
    int bt = gwid / NPAIR;
    int vox0 = (gwid - bt * NPAIR) * 32;
    const float* b0 = occ + (size_t)bt * CO * NVOX + (size_t)q * 8 * NVOX + vox0 + r;
    v4f acc0[3] = {{0.f,0.f,0.f,0.f},{0.f,0.f,0.f,0.f},{0.f,0.f,0.f,0.f}};
    v4f acc1[3] = {{0.f,0.f,0.f,0.f},{0.f,0.f,0.f,0.f},{0.f,0.f,0.f,0.f}};
#pragma unroll
    for (int s = 0; s < 8; ++s) {
        float t0[8], t1[8];
#pragma unroll
        for (int j = 0; j < 8; ++j) {
            const float* a = b0 + (size_t)(s * 32 + j) * NVOX;
            t0[j] = __builtin_nontemporal_load(a);
            t1[j] = __builtin_nontemporal_load(a + 16);
        }
        bfrag8 bf0, bf1;
#pragma unroll
        for (int j = 0; j < 8; ++j) { bf0[j] = f2bf(t0[j]); bf1[j] = f2bf(t1[j]); }
#pragma unroll
        for (int gt = 0; gt < 3; ++gt) {
            acc0[gt] = __builtin_amdgcn_mfma_f32_16x16x32_bf16(wfr[s][gt], bf0, acc0[gt], 0, 0, 0);
            acc1[gt] = __builtin_amdgcn_mfma_f32_16x16x32_bf16(wfr[s][gt], bf1, acc1[gt], 0, 0, 0);
        }
    }
    float* o0 = P + ((size_t)bt * NVOX + vox0 + r) * CG + q * 4;
    float* o1 = o0 + (size_t)16 * CG;
#pragma unroll
    for (int gt = 0; gt < 3; ++gt) {
        *reinterpret_cast<v4f*>(o0 + 16 * gt) = acc0[gt];
        *reinterpret_cast<v4f*>(o1 + 16 * gt) = acc1[gt];
    }
}

// ---------------------------------------------------------------------------
// Pass 4: trilinear gather from P + bias -> occ_to_gs output.
// ---------------------------------------------------------------------------
__global__ __launch_bounds__(256) void k_gather(
    const float* __restrict__ pts, const float* __restrict__ P,
    const float* __restrict__ bo2g, float* __restrict__ out1)
{
    int idx = blockIdx.x * 256 + threadIdx.x;     // (pn)*CG + g
    int g  = idx % CG;
    int pn = idx / CG;
    int bt = pn / NPT;
    float x = pts[pn * 3 + 0];
    float y = pts[pn * 3 + 1];
    float z = pts[pn * 3 + 2];
    float gx = (x - GMX) / 80.0f * 2.0f - 1.0f;
    float gy = (y - GMY) / 80.0f * 2.0f - 1.0f;
    float gz = (z - GMZ) / 8.0f  * 2.0f - 1.0f;
    float px = ((gx + 1.0f) * (float)NXc - 1.0f) * 0.5f;
    float py = ((gy + 1.0f) * (float)NYc - 1.0f) * 0.5f;
    float pz = ((gz + 1.0f) * (float)NZc - 1.0f) * 0.5f;
    float fx = floorf(px), fy = floorf(py), fz = floorf(pz);
    float rx = px - fx, ry = py - fy, rz = pz - fz;
    int x0 = (int)fx, y0 = (int)fy, z0 = (int)fz;
    float acc = bo2g[g];
    const float* Pb = P + (size_t)bt * NVOX * CG;
#pragma unroll
    for (int dz = 0; dz <= 1; ++dz) {
        int zi = z0 + dz;
        if (zi < 0 || zi >= NZc) continue;
        float wz = dz ? rz : 1.0f - rz;
#pragma unroll
        for (int dy = 0; dy <= 1; ++dy) {
            int yi = y0 + dy;
            if (yi < 0 || yi >= NYc) continue;
            float wy = dy ? ry : 1.0f - ry;
#pragma unroll
            for (int dx = 0; dx <= 1; ++dx) {
                int xi = x0 + dx;
                if (xi < 0 || xi >= NXc) continue;
                float wx = dx ? rx : 1.0f - rx;
                float w = (wx * wy) * wz;
                int lin = zi * (NYc * NXc) + yi * NXc + xi;
                acc = fmaf(w, Pb[(size_t)lin * CG + g], acc);
            }
        }
    }
    out1[idx] = acc;
}

// ---------------------------------------------------------------------------
// Pass 5: sparse GEMM — compact256[slot][256] = mean[slot][48] @ Wg2o + b.
// ---------------------------------------------------------------------------
__global__ __launch_bounds__(256) void k_gemm(
    const float* __restrict__ compactM, const float* __restrict__ cnt,
    const int* __restrict__ list, const int* __restrict__ noccp,
    const float* __restrict__ Wg2o, const float* __restrict__ bg2o,
    float* __restrict__ compact256)
{
    int nocc = *noccp;
    int s0 = blockIdx.x * 32;
    if (s0 >= nocc) return;                      // uniform per block
    __shared__ float Wl[CG * CO];                // 48 KB, [k][c]
    __shared__ float Ml[32 * CG];                // 6 KB means
    for (int j = threadIdx.x; j < CG * CO; j += 256) Wl[j] = Wg2o[j];
    for (int j = threadIdx.x; j < 32 * CG; j += 256) {
        int v = j / CG, k = j - v * CG;
        int slot = s0 + v;
        float m = 0.f;
        if (slot < nocc) {
            int btvox = list[slot];
            m = compactM[(size_t)slot * CG + k] / cnt[btvox];
        }
        Ml[j] = m;
    }
    __syncthreads();
    int wid = threadIdx.x >> 6, l = threadIdx.x & 63;
    int vb = wid * 8;
    float4 bias = *reinterpret_cast<const float4*>(&bg2o[4 * l]);
    float acc[8][4];
#pragma unroll
    for (int v = 0; v < 8; ++v) {
        acc[v][0] = bias.x; acc[v][1] = bias.y; acc[v][2] = bias.z; acc[v][3] = bias.w;
    }
    for (int k = 0; k < CG; k += 4) {
        float4 w0 = *reinterpret_cast<const float4*>(&Wl[(k + 0) * CO + 4 * l]);
        float4 w1 = *reinterpret_cast<const float4*>(&Wl[(k + 1) * CO + 4 * l]);
        float4 w2 = *reinterpret_cast<const float4*>(&Wl[(k + 2) * CO + 4 * l]);
        float4 w3 = *reinterpret_cast<const float4*>(&Wl[(k + 3) * CO + 4 * l]);
#pragma unroll
        for (int v = 0; v < 8; ++v) {
            float4 m4 = *reinterpret_cast<const float4*>(&Ml[(vb + v) * CG + k]);
            acc[v][0] = fmaf(m4.x, w0.x, acc[v][0]);
            acc[v][1] = fmaf(m4.x, w0.y, acc[v][1]);
            acc[v][2] = fmaf(m4.x, w0.z, acc[v][2]);
            acc[v][3] = fmaf(m4.x, w0.w, acc[v][3]);
            acc[v][0] = fmaf(m4.y, w1.x, acc[v][0]);
            acc[v][1] = fmaf(m4.y, w1.y, acc[v][1]);
            acc[v][2] = fmaf(m4.y, w1.z, acc[v][2]);
            acc[v][3] = fmaf(m4.y, w1.w, acc[v][3]);
            acc[v][0] = fmaf(m4.z, w2.x, acc[v][0]);
            acc[v][1] = fmaf(m4.z, w2.y, acc[v][1]);
            acc[v][2] = fmaf(m4.z, w2.z, acc[v][2]);
            acc[v][3] = fmaf(m4.z, w2.w, acc[v][3]);
            acc[v][0] = fmaf(m4.w, w3.x, acc[v][0]);
            acc[v][1] = fmaf(m4.w, w3.y, acc[v][1]);
            acc[v][2] = fmaf(m4.w, w3.z, acc[v][2]);
            acc[v][3] = fmaf(m4.w, w3.w, acc[v][3]);
        }
    }
#pragma unroll
    for (int v = 0; v < 8; ++v) {
        int slot = s0 + vb + v;
        if (slot < nocc) {
            float4 rr; rr.x = acc[v][0]; rr.y = acc[v][1]; rr.z = acc[v][2]; rr.w = acc[v][3];
            *reinterpret_cast<float4*>(&compact256[(size_t)slot * CO + 4 * l]) = rr;
        }
    }
}

// ---------------------------------------------------------------------------
// Pass 6: dense writer. Thread -> 4 consecutive vox; loop 32 channels.
// ---------------------------------------------------------------------------
__global__ __launch_bounds__(256) void k_writer(
    const int* __restrict__ invmap, const float* __restrict__ compact256,
    float* __restrict__ out0)
{
    int bt = blockIdx.z;
    int c0 = blockIdx.y * 32;
    int v0 = blockIdx.x * 1024 + threadIdx.x * 4;
    if (v0 >= NVOX) return;
    int4 sp = *reinterpret_cast<const int4*>(&invmap[bt * NVOX + v0]);
    const float* r0 = compact256 + (size_t)(sp.x - 1) * CO;
    const float* r1 = compact256 + (size_t)(sp.y - 1) * CO;
    const float* r2 = compact256 + (size_t)(sp.z - 1) * CO;
    const float* r3 = compact256 + (size_t)(sp.w - 1) * CO;
    float* ob = out0 + (size_t)bt * CO * NVOX + (size_t)c0 * NVOX + v0;
#pragma unroll 4
    for (int ci = 0; ci < 32; ++ci) {
        int c = c0 + ci;
        v4f val;
        val.x = sp.x ? r0[c] : 0.f;
        val.y = sp.y ? r1[c] : 0.f;
        val.z = sp.z ? r2[c] : 0.f;
        val.w = sp.w ? r3[c] : 0.f;
        __builtin_nontemporal_store(val, reinterpret_cast<v4f*>(ob + (size_t)ci * NVOX));
    }
}

// ---------------------------------------------------------------------------
extern "C" void kernel_launch(void* const* d_in, const int* in_sizes, int n_in,
                              void* d_out, int out_size, void* d_ws, size_t ws_size,
                              hipStream_t stream)
{
    const float* centers = (const float*)d_in[0];
    const float* feats   = (const float*)d_in[1];
    const float* occ     = (const float*)d_in[2];
    const float* Wg2o    = (const float*)d_in[3];
    const float* bg2o    = (const float*)d_in[4];
    const float* Wo2g    = (const float*)d_in[5];
    const float* bo2g    = (const float*)d_in[6];

    float* out  = (float*)d_out;
    float* out0 = out;                                   // [BT][CO][NVOX]
    float* out1 = out + (size_t)BT * CO * NVOX;          // [BT][NPT][CG]
    // f32 P in tail of out0: written by volproj, read by gather, overwritten
    // by writer (stream-ordered).
    float* P    = out0 + (size_t)BT * CO * NVOX - (size_t)BT * NVOX * CG;
    // Packed bf16 W fragments at head of out1 (24 KB): written by k_init,
    // read by k_volproj, then fully overwritten by k_gather.
    short* wp   = (short*)out1;

    // ws layout: zeroed region first (cnt, nocc, invmap, compactM), then rest.
    char* w = (char*)d_ws;
    float* cnt       = (float*)w;                 w += (size_t)BT * NVOX * 4;       // 800000
    int*   nocc      = (int*)w;                   w += 256;
    int*   invmap    = (int*)w;                   w += (size_t)BT * NVOX * 4;       // 800000
    float* compactM  = (float*)w;                 w += (size_t)MAXS * CG * 4;       // 6488064
    size_t zbytes = (size_t)BT * NVOX * 4 + 256 + (size_t)BT * NVOX * 4
                  + (size_t)MAXS * CG * 4;       // 8,088,320 (16B-divisible)
    int*   ptvox     = (int*)w;                   w += (size_t)NPTS * 4;            // 135168
    int*   list      = (int*)w;                   w += (size_t)MAXS * 4;            // 135168
    float* compact256 = (float*)w;               // MAXS*CO*4 = 34603008

    k_init<<<1025, 256, 0, stream>>>((v4f*)d_ws, (int)(zbytes / 16), Wo2g, wp);
    k_count<<<NPTS / 256, 256, 0, stream>>>(centers, cnt, nocc, invmap, ptvox, list);
    k_scatterM<<<NPTS * CG / 256, 256, 0, stream>>>(feats, ptvox, invmap, compactM);
    k_volproj<<<(BT * NPAIR + 3) / 4, 256, 0, stream>>>(occ, wp, P);
    k_gather<<<NPTS * CG / 256, 256, 0, stream>>>(centers, P, bo2g, out1);
    k_gemm<<<(MAXS + 31) / 32, 256, 0, stream>>>(compactM, cnt, list, nocc, Wg2o, bg2o, compact256);
    k_writer<<<dim3((NVOX + 1023) / 1024, 8, BT), 256, 0, stream>>>(invmap, compact256, out0);
}

// Round 10
// 175.426 us; speedup vs baseline: 1.1693x; 1.0122x over previous
//
#include <hip/hip_runtime.h>
#include <hip/hip_bf16.h>

typedef float v4f __attribute__((ext_vector_type(4)));
typedef short bfrag8 __attribute__((ext_vector_type(8)));

// Problem constants (match reference)
constexpr int NXc = 100, NYc = 100, NZc = 10;
constexpr int NVOX = NZc * NYc * NXc;      // 100000
constexpr int CO = 256, CG = 48;
constexpr int BT = 2;
constexpr int NPT = 6 * 32 * 88;           // 16896 points per bt
constexpr int NPTS = BT * NPT;             // 33792
constexpr int MAXS = NPTS;                 // max occupied voxels
constexpr int NW64 = (NVOX + 63) / 64;     // 1563 64-vox wave-groups per bt
constexpr float GMX = -40.0f, GMY = -40.0f, GMZ = -2.0f;
constexpr float VOXEL = 0.8f;

static __device__ __forceinline__ short f2bf(float f) {
    __hip_bfloat16 h = __float2bfloat16(f);
    return __builtin_bit_cast(short, h);
}

// ---------------------------------------------------------------------------
// Pass 0: blocks 0..1023 zero the scatter scratch; block 1024 packs Wo2g^T
// into bf16 MFMA A-fragments: lane l slot j holds W[k][g],
// k = s*32 + (l>>4)*8 + j, g = gt*16 + (l&15); wp[((s*3+gt)*64 + l)*8 + j].
// ---------------------------------------------------------------------------
__global__ __launch_bounds__(256) void k_init(
    v4f* __restrict__ p, int n16,
    const float* __restrict__ Wo2g, short* __restrict__ wp)
{
    if (blockIdx.x < 1024) {
        v4f z = {0.f, 0.f, 0.f, 0.f};
        for (int i = blockIdx.x * 256 + threadIdx.x; i < n16; i += 1024 * 256)
            p[i] = z;
    } else {
        for (int e = threadIdx.x; e < 8 * 3 * 64 * 8; e += 256) {
            int j  = e & 7;
            int l  = (e >> 3) & 63;
            int ft = e >> 9;                      // s*3 + gt
            int s  = ft / 3, gt = ft - 3 * s;
            int k  = s * 32 + (l >> 4) * 8 + j;
            int g  = gt * 16 + (l & 15);
            wp[e] = f2bf(Wo2g[k * CG + g]);
        }
    }
}

// ---------------------------------------------------------------------------
// Pass 1: per point -> voxel; count + assign compact slots + slot list.
// ---------------------------------------------------------------------------
__global__ __launch_bounds__(256) void k_count(
    const float* __restrict__ pts, float* __restrict__ cnt,
    int* __restrict__ nocc, int* __restrict__ invmap, int* __restrict__ ptvox,
    int* __restrict__ list)
{
    int pn = blockIdx.x * 256 + threadIdx.x;      // < NPTS (exact grid)
    float x = pts[pn * 3 + 0];
    float y = pts[pn * 3 + 1];
    float z = pts[pn * 3 + 2];
    int ix = (int)floorf((x - GMX) / VOXEL);
    int iy = (int)floorf((y - GMY) / VOXEL);
    int iz = (int)floorf((z - GMZ) / VOXEL);
    bool valid = (ix >= 0 && ix < NXc && iy >= 0 && iy < NYc && iz >= 0 && iz < NZc);
    if (!valid) { ptvox[pn] = -1; return; }
    int bt = pn / NPT;
    int btvox = bt * NVOX + iz * (NYc * NXc) + iy * NXc + ix;
    ptvox[pn] = btvox;
    float old = atomicAdd(&cnt[btvox], 1.0f);
    if (old == 0.0f) {
        int s = atomicAdd(nocc, 1);
        invmap[btvox] = s + 1;                    // 0 = empty
        list[s] = btvox;
    }
}

// ---------------------------------------------------------------------------
// Pass 2: scatter-add 48-dim features into compact mean buffer.
// ---------------------------------------------------------------------------
__global__ __launch_bounds__(256) void k_scatterM(
    const float* __restrict__ feats, const int* __restrict__ ptvox,
    const int* __restrict__ invmap, float* __restrict__ compactM)
{
    int idx = blockIdx.x * 256 + threadIdx.x;     // (pn)*CG + k, < NPTS*CG
    int k  = idx % CG;
    int pn = idx / CG;
    int bv = ptvox[pn];
    if (bv < 0) return;
    int slot = invmap[bv] - 1;
    atomicAdd(&compactM[(size_t)slot * CG + k], feats[idx]);
}

// ---------------------------------------------------------------------------
// Pass 3: P[bt][vox][48] (f32) = occ[bt][:,vox]^T @ Wo2g via bf16 MFMA.
// One wave per 64 vox: lane loads dwordx4 (4 vox) per channel -> 256 B
// contiguous per 16-lane plane-visit (4x fewer, 4x larger requests than
// the 64 B sliver pattern that measured ~1.9 TB/s). MFMA tile t takes
// col r <-> vox0+4r+t; stores write each acc row to its interleaved voxel.
// Last wave per bt: load base clamped to NVOX-4, stores predicated.
// C/D layout (m89): col = lane&15, row = (lane>>4)*4+reg (g).
// ---------------------------------------------------------------------------
__global__ __launch_bounds__(256) void k_volproj(
    const float* __restrict__ occ, const short* __restrict__ wp,
    float* __restrict__ P)
{
    int gwid = (blockIdx.x * 256 + threadIdx.x) >> 6;
    if (gwid >= BT * NW64) return;
    int l = threadIdx.x & 63;
    int q = l >> 4, r = l & 15;
    const bfrag8* wf = reinterpret_cast<const bfrag8*>(wp);
    bfrag8 wfr[8][3];
#pragma unroll
    for (int s = 0; s < 8; ++s)
#pragma unroll
        for (int gt = 0; gt < 3; ++gt)
            wfr[s][gt] = wf[(s * 3 + gt) * 64 + l];
    int bt = gwid / NW64;
    int vox0 = (gwid - bt * NW64) * 64;
    int vbase = vox0 + 4 * r;
    int vload = vbase > NVOX - 4 ? NVOX - 4 : vbase;     // clamp (last wave only)
    const float* b0 = occ + (size_t)bt * CO * NVOX + (size_t)q * 8 * NVOX + vload;
    v4f acc[4][3];
#pragma unroll
    for (int t = 0; t < 4; ++t)
#pragma unroll
        for (int gt = 0; gt < 3; ++gt)
            acc[t][gt] = v4f{0.f, 0.f, 0.f, 0.f};
#pragma unroll
    for (int s = 0; s < 8; ++s) {
        v4f vj[8];
#pragma unroll
        for (int j = 0; j < 8; ++j)
            vj[j] = *reinterpret_cast<const v4f*>(b0 + (size_t)(s * 32 + j) * NVOX);
        bfrag8 bf[4];
#pragma unroll
        for (int t = 0; t < 4; ++t)
#pragma unroll
            for (int j = 0; j < 8; ++j)
                bf[t][j] = f2bf(vj[j][t]);
#pragma unroll
        for (int t = 0; t < 4; ++t)
#pragma unroll
            for (int gt = 0; gt < 3; ++gt)
                acc[t][gt] = __builtin_amdgcn_mfma_f32_16x16x32_bf16(
                    wfr[s][gt], bf[t], acc[t][gt], 0, 0, 0);
    }
    float* o = P + ((size_t)bt * NVOX + vbase) * CG + q * 4;
#pragma unroll
    for (int t = 0; t < 4; ++t) {
        if (vbase + t < NVOX) {
#pragma unroll
            for (int gt = 0; gt < 3; ++gt)
                *reinterpret_cast<v4f*>(o + t * CG + gt * 16) = acc[t][gt];
        }
    }
}

// ---------------------------------------------------------------------------
// Pass 4: trilinear gather from P + bias -> occ_to_gs output.
// ---------------------------------------------------------------------------
__global__ __launch_bounds__(256) void k_gather(
    const float* __restrict__ pts, const float* __restrict__ P,
    const float* __restrict__ bo2g, float* __restrict__ out1)
{
    int idx = blockIdx.x * 256 + threadIdx.x;     // (pn)*CG + g
    int g  = idx % CG;
    int pn = idx / CG;
    int bt = pn / NPT;
    float x = pts[pn * 3 + 0];
    float y = pts[pn * 3 + 1];
    float z = pts[pn * 3 + 2];
    float gx = (x - GMX) / 80.0f * 2.0f - 1.0f;
    float gy = (y - GMY) / 80.0f * 2.0f - 1.0f;
    float gz = (z - GMZ) / 8.0f  * 2.0f - 1.0f;
    float px = ((gx + 1.0f) * (float)NXc - 1.0f) * 0.5f;
    float py = ((gy + 1.0f) * (float)NYc - 1.0f) * 0.5f;
    float pz = ((gz + 1.0f) * (float)NZc - 1.0f) * 0.5f;
    float fx = floorf(px), fy = floorf(py), fz = floorf(pz);
    float rx = px - fx, ry = py - fy, rz = pz - fz;
    int x0 = (int)fx, y0 = (int)fy, z0 = (int)fz;
    float acc = bo2g[g];
    const float* Pb = P + (size_t)bt * NVOX * CG;
#pragma unroll
    for (int dz = 0; dz <= 1; ++dz) {
        int zi = z0 + dz;
        if (zi < 0 || zi >= NZc) continue;
        float wz = dz ? rz : 1.0f - rz;
#pragma unroll
        for (int dy = 0; dy <= 1; ++dy) {
            int yi = y0 + dy;
            if (yi < 0 || yi >= NYc) continue;
            float wy = dy ? ry : 1.0f - ry;
#pragma unroll
            for (int dx = 0; dx <= 1; ++dx) {
                int xi = x0 + dx;
                if (xi < 0 || xi >= NXc) continue;
                float wx = dx ? rx : 1.0f - rx;
                float w = (wx * wy) * wz;
                int lin = zi * (NYc * NXc) + yi * NXc + xi;
                acc = fmaf(w, Pb[(size_t)lin * CG + g], acc);
            }
        }
    }
    out1[idx] = acc;
}

// ---------------------------------------------------------------------------
// Pass 5: sparse GEMM — compact256[slot][256] = mean[slot][48] @ Wg2o + b.
// ---------------------------------------------------------------------------
__global__ __launch_bounds__(256) void k_gemm(
    const float* __restrict__ compactM, const float* __restrict__ cnt,
    const int* __restrict__ list, const int* __restrict__ noccp,
    const float* __restrict__ Wg2o, const float* __restrict__ bg2o,
    float* __restrict__ compact256)
{
    int nocc = *noccp;
    int s0 = blockIdx.x * 32;
    if (s0 >= nocc) return;                      // uniform per block
    __shared__ float Wl[CG * CO];                // 48 KB, [k][c]
    __shared__ float Ml[32 * CG];                // 6 KB means
    for (int j = threadIdx.x; j < CG * CO; j += 256) Wl[j] = Wg2o[j];
    for (int j = threadIdx.x; j < 32 * CG; j += 256) {
        int v = j / CG, k = j - v * CG;
        int slot = s0 + v;
        float m = 0.f;
        if (slot < nocc) {
            int btvox = list[slot];
            m = compactM[(size_t)slot * CG + k] / cnt[btvox];
        }
        Ml[j] = m;
    }
    __syncthreads();
    int wid = threadIdx.x >> 6, l = threadIdx.x & 63;
    int vb = wid * 8;
    float4 bias = *reinterpret_cast<const float4*>(&bg2o[4 * l]);
    float acc[8][4];
#pragma unroll
    for (int v = 0; v < 8; ++v) {
        acc[v][0] = bias.x; acc[v][1] = bias.y; acc[v][2] = bias.z; acc[v][3] = bias.w;
    }
    for (int k = 0; k < CG; k += 4) {
        float4 w0 = *reinterpret_cast<const float4*>(&Wl[(k + 0) * CO + 4 * l]);
        float4 w1 = *reinterpret_cast<const float4*>(&Wl[(k + 1) * CO + 4 * l]);
        float4 w2 = *reinterpret_cast<const float4*>(&Wl[(k + 2) * CO + 4 * l]);
        float4 w3 = *reinterpret_cast<const float4*>(&Wl[(k + 3) * CO + 4 * l]);
#pragma unroll
        for (int v = 0; v < 8; ++v) {
            float4 m4 = *reinterpret_cast<const float4*>(&Ml[(vb + v) * CG + k]);
            acc[v][0] = fmaf(m4.x, w0.x, acc[v][0]);
            acc[v][1] = fmaf(m4.x, w0.y, acc[v][1]);
            acc[v][2] = fmaf(m4.x, w0.z, acc[v][2]);
            acc[v][3] = fmaf(m4.x, w0.w, acc[v][3]);
            acc[v][0] = fmaf(m4.y, w1.x, acc[v][0]);
            acc[v][1] = fmaf(m4.y, w1.y, acc[v][1]);
            acc[v][2] = fmaf(m4.y, w1.z, acc[v][2]);
            acc[v][3] = fmaf(m4.y, w1.w, acc[v][3]);
            acc[v][0] = fmaf(m4.z, w2.x, acc[v][0]);
            acc[v][1] = fmaf(m4.z, w2.y, acc[v][1]);
            acc[v][2] = fmaf(m4.z, w2.z, acc[v][2]);
            acc[v][3] = fmaf(m4.z, w2.w, acc[v][3]);
            acc[v][0] = fmaf(m4.w, w3.x, acc[v][0]);
            acc[v][1] = fmaf(m4.w, w3.y, acc[v][1]);
            acc[v][2] = fmaf(m4.w, w3.z, acc[v][2]);
            acc[v][3] = fmaf(m4.w, w3.w, acc[v][3]);
        }
    }
#pragma unroll
    for (int v = 0; v < 8; ++v) {
        int slot = s0 + vb + v;
        if (slot < nocc) {
            float4 rr; rr.x = acc[v][0]; rr.y = acc[v][1]; rr.z = acc[v][2]; rr.w = acc[v][3];
            *reinterpret_cast<float4*>(&compact256[(size_t)slot * CO + 4 * l]) = rr;
        }
    }
}

// ---------------------------------------------------------------------------
// Pass 6: dense writer. Thread -> 4 consecutive vox; loop 32 channels.
// ---------------------------------------------------------------------------
__global__ __launch_bounds__(256) void k_writer(
    const int* __restrict__ invmap, const float* __restrict__ compact256,
    float* __restrict__ out0)
{
    int bt = blockIdx.z;
    int c0 = blockIdx.y * 32;
    int v0 = blockIdx.x * 1024 + threadIdx.x * 4;
    if (v0 >= NVOX) return;
    int4 sp = *reinterpret_cast<const int4*>(&invmap[bt * NVOX + v0]);
    const float* r0 = compact256 + (size_t)(sp.x - 1) * CO;
    const float* r1 = compact256 + (size_t)(sp.y - 1) * CO;
    const float* r2 = compact256 + (size_t)(sp.z - 1) * CO;
    const float* r3 = compact256 + (size_t)(sp.w - 1) * CO;
    float* ob = out0 + (size_t)bt * CO * NVOX + (size_t)c0 * NVOX + v0;
#pragma unroll 4
    for (int ci = 0; ci < 32; ++ci) {
        int c = c0 + ci;
        v4f val;
        val.x = sp.x ? r0[c] : 0.f;
        val.y = sp.y ? r1[c] : 0.f;
        val.z = sp.z ? r2[c] : 0.f;
        val.w = sp.w ? r3[c] : 0.f;
        __builtin_nontemporal_store(val, reinterpret_cast<v4f*>(ob + (size_t)ci * NVOX));
    }
}

// ---------------------------------------------------------------------------
extern "C" void kernel_launch(void* const* d_in, const int* in_sizes, int n_in,
                              void* d_out, int out_size, void* d_ws, size_t ws_size,
                              hipStream_t stream)
{
    const float* centers = (const float*)d_in[0];
    const float* feats   = (const float*)d_in[1];
    const float* occ     = (const float*)d_in[2];
    const float* Wg2o    = (const float*)d_in[3];
    const float* bg2o    = (const float*)d_in[4];
    const float* Wo2g    = (const float*)d_in[5];
    const float* bo2g    = (const float*)d_in[6];

    float* out  = (float*)d_out;
    float* out0 = out;                                   // [BT][CO][NVOX]
    float* out1 = out + (size_t)BT * CO * NVOX;          // [BT][NPT][CG]
    // f32 P in tail of out0: written by volproj, read by gather, overwritten
    // by writer (stream-ordered). Last-wave spill past P lands in out1's
    // first 6 KB, which gather fully overwrites afterwards.
    float* P    = out0 + (size_t)BT * CO * NVOX - (size_t)BT * NVOX * CG;
    // Packed bf16 W fragments at head of out1 (24 KB): written by k_init,
    // read by k_volproj, then fully overwritten by k_gather.
    short* wp   = (short*)out1;

    // ws layout: zeroed region first (cnt, nocc, invmap, compactM), then rest.
    char* w = (char*)d_ws;
    float* cnt       = (float*)w;                 w += (size_t)BT * NVOX * 4;       // 800000
    int*   nocc      = (int*)w;                   w += 256;
    int*   invmap    = (int*)w;                   w += (size_t)BT * NVOX * 4;       // 800000
    float* compactM  = (float*)w;                 w += (size_t)MAXS * CG * 4;       // 6488064
    size_t zbytes = (size_t)BT * NVOX * 4 + 256 + (size_t)BT * NVOX * 4
                  + (size_t)MAXS * CG * 4;       // 8,088,320 (16B-divisible)
    int*   ptvox     = (int*)w;                   w += (size_t)NPTS * 4;            // 135168
    int*   list      = (int*)w;                   w += (size_t)MAXS * 4;            // 135168
    float* compact256 = (float*)w;               // MAXS*CO*4 = 34603008

    k_init<<<1025, 256, 0, stream>>>((v4f*)d_ws, (int)(zbytes / 16), Wo2g, wp);
    k_count<<<NPTS / 256, 256, 0, stream>>>(centers, cnt, nocc, invmap, ptvox, list);
    k_scatterM<<<NPTS * CG / 256, 256, 0, stream>>>(feats, ptvox, invmap, compactM);
    k_volproj<<<(BT * NW64 + 3) / 4, 256, 0, stream>>>(occ, wp, P);
    k_gather<<<NPTS * CG / 256, 256, 0, stream>>>(centers, P, bo2g, out1);
    k_gemm<<<(MAXS + 31) / 32, 256, 0, stream>>>(compactM, cnt, list, nocc, Wg2o, bg2o, compact256);
    k_writer<<<dim3((NVOX + 1023) / 1024, 8, BT), 256, 0, stream>>>(invmap, compact256, out0);
}

// Round 11
// 175.084 us; speedup vs baseline: 1.1715x; 1.0020x over previous
//
#include <hip/hip_runtime.h>
#include <hip/hip_bf16.h>

typedef float v4f __attribute__((ext_vector_type(4)));
typedef short v4s __attribute__((ext_vector_type(4)));
typedef short bfrag8 __attribute__((ext_vector_type(8)));

// Problem constants (match reference)
constexpr int NXc = 100, NYc = 100, NZc = 10;
constexpr int NVOX = NZc * NYc * NXc;      // 100000
constexpr int CO = 256, CG = 48;
constexpr int BT = 2;
constexpr int NPT = 6 * 32 * 88;           // 16896 points per bt
constexpr int NPTS = BT * NPT;             // 33792
constexpr int MAXS = NPTS;                 // max occupied voxels
constexpr int NTB = (NVOX + 255) / 256;    // 391 256-vox tiles per bt
constexpr float GMX = -40.0f, GMY = -40.0f, GMZ = -2.0f;
constexpr float VOXEL = 0.8f;

static __device__ __forceinline__ short f2bf(float f) {
    __hip_bfloat16 h = __float2bfloat16(f);
    return __builtin_bit_cast(short, h);
}

// ---------------------------------------------------------------------------
// Pass 0: blocks 0..1023 zero the scatter scratch; block 1024 packs Wo2g^T
// into bf16 MFMA A-fragments: lane l slot j holds W[k][g],
// k = s*32 + (l>>4)*8 + j, g = gt*16 + (l&15); wp[((s*3+gt)*64 + l)*8 + j].
// ---------------------------------------------------------------------------
__global__ __launch_bounds__(256) void k_init(
    v4f* __restrict__ p, int n16,
    const float* __restrict__ Wo2g, short* __restrict__ wp)
{
    if (blockIdx.x < 1024) {
        v4f z = {0.f, 0.f, 0.f, 0.f};
        for (int i = blockIdx.x * 256 + threadIdx.x; i < n16; i += 1024 * 256)
            p[i] = z;
    } else {
        for (int e = threadIdx.x; e < 8 * 3 * 64 * 8; e += 256) {
            int j  = e & 7;
            int l  = (e >> 3) & 63;
            int ft = e >> 9;                      // s*3 + gt
            int s  = ft / 3, gt = ft - 3 * s;
            int k  = s * 32 + (l >> 4) * 8 + j;
            int g  = gt * 16 + (l & 15);
            wp[e] = f2bf(Wo2g[k * CG + g]);
        }
    }
}

// ---------------------------------------------------------------------------
// Pass 1: per point -> voxel; count + assign compact slots + slot list.
// ---------------------------------------------------------------------------
__global__ __launch_bounds__(256) void k_count(
    const float* __restrict__ pts, float* __restrict__ cnt,
    int* __restrict__ nocc, int* __restrict__ invmap, int* __restrict__ ptvox,
    int* __restrict__ list)
{
    int pn = blockIdx.x * 256 + threadIdx.x;      // < NPTS (exact grid)
    float x = pts[pn * 3 + 0];
    float y = pts[pn * 3 + 1];
    float z = pts[pn * 3 + 2];
    int ix = (int)floorf((x - GMX) / VOXEL);
    int iy = (int)floorf((y - GMY) / VOXEL);
    int iz = (int)floorf((z - GMZ) / VOXEL);
    bool valid = (ix >= 0 && ix < NXc && iy >= 0 && iy < NYc && iz >= 0 && iz < NZc);
    if (!valid) { ptvox[pn] = -1; return; }
    int bt = pn / NPT;
    int btvox = bt * NVOX + iz * (NYc * NXc) + iy * NXc + ix;
    ptvox[pn] = btvox;
    float old = atomicAdd(&cnt[btvox], 1.0f);
    if (old == 0.0f) {
        int s = atomicAdd(nocc, 1);
        invmap[btvox] = s + 1;                    // 0 = empty
        list[s] = btvox;
    }
}

// ---------------------------------------------------------------------------
// Pass 2: scatter-add 48-dim features into compact mean buffer.
// ---------------------------------------------------------------------------
__global__ __launch_bounds__(256) void k_scatterM(
    const float* __restrict__ feats, const int* __restrict__ ptvox,
    const int* __restrict__ invmap, float* __restrict__ compactM)
{
    int idx = blockIdx.x * 256 + threadIdx.x;     // (pn)*CG + k, < NPTS*CG
    int k  = idx % CG;
    int pn = idx / CG;
    int bv = ptvox[pn];
    if (bv < 0) return;
    int slot = invmap[bv] - 1;
    atomicAdd(&compactM[(size_t)slot * CG + k], feats[idx]);
}

// ---------------------------------------------------------------------------
// Pass 3: P[bt][vox][48] (f32) = occ[bt][:,vox]^T @ Wo2g via bf16 MFMA.
// Canonical GEMM structure: block = 256 thr / 256 vox; K-tiles of 32
// channels staged through double-buffered bf16 LDS. All blocks sweep the
// channel planes in the SAME order (s=0..7), each owning a fixed contiguous
// 1 KB window -> plane-sequential DRAM access chip-wide (vs R10's scattered
// per-wave plane hopping). Load lane-map (thread=vox) is decoupled from the
// MFMA fragment map via the LDS transpose.
// k-bijection (both A and B): k = s*32 + q*8 + j (identical to R10 ->
// bit-identical numerics). C/D (m89): col=lane&15 (vox), row=q*4+reg (g).
// ---------------------------------------------------------------------------
__global__ __launch_bounds__(256) void k_volproj(
    const float* __restrict__ occ, const short* __restrict__ wp,
    float* __restrict__ P)
{
    constexpr int LSTR = 40;                      // shorts; 80 B rows (b128-aligned)
    __shared__ short lds[2][256 * LSTR];          // 2 x 20 KB
    int gb = blockIdx.x;
    int bt = gb / NTB;
    int vox0 = (gb - bt * NTB) * 256;
    int tid = threadIdx.x;
    int l = tid & 63, w = tid >> 6;
    int q = l >> 4, r = l & 15;
    const float* ob = occ + (size_t)bt * CO * NVOX;
    int vme = vox0 + tid;
    if (vme > NVOX - 1) vme = NVOX - 1;           // clamp (tail block only)
    const bfrag8* wf = reinterpret_cast<const bfrag8*>(wp);

    v4f acc[4][3];
#pragma unroll
    for (int t = 0; t < 4; ++t)
#pragma unroll
        for (int gt = 0; gt < 3; ++gt)
            acc[t][gt] = v4f{0.f, 0.f, 0.f, 0.f};

    float ld[32];
    // prologue: fetch K-tile 0 and stage into buffer 0
#pragma unroll
    for (int c = 0; c < 32; ++c)
        ld[c] = ob[(size_t)c * NVOX + vme];
#pragma unroll
    for (int cg = 0; cg < 8; ++cg) {
        v4s pk;
#pragma unroll
        for (int i = 0; i < 4; ++i) pk[i] = f2bf(ld[cg * 4 + i]);
        *reinterpret_cast<v4s*>(&lds[0][tid * LSTR + cg * 4]) = pk;
    }

    for (int s = 0; s < 8; ++s) {
        __syncthreads();                          // buf[s&1] ready
        if (s < 7) {                              // issue next K-tile loads
#pragma unroll
            for (int c = 0; c < 32; ++c)
                ld[c] = ob[(size_t)((s + 1) * 32 + c) * NVOX + vme];
        }
        const short* buf = lds[s & 1];
#pragma unroll
        for (int t = 0; t < 4; ++t) {
            bfrag8 bfr = *reinterpret_cast<const bfrag8*>(
                &buf[(w * 64 + t * 16 + r) * LSTR + q * 8]);
#pragma unroll
            for (int gt = 0; gt < 3; ++gt)
                acc[t][gt] = __builtin_amdgcn_mfma_f32_16x16x32_bf16(
                    wf[(s * 3 + gt) * 64 + l], bfr, acc[t][gt], 0, 0, 0);
        }
        if (s < 7) {                              // stage next tile (other buffer)
            short* nb = lds[(s + 1) & 1];
#pragma unroll
            for (int cg = 0; cg < 8; ++cg) {
                v4s pk;
#pragma unroll
                for (int i = 0; i < 4; ++i) pk[i] = f2bf(ld[cg * 4 + i]);
                *reinterpret_cast<v4s*>(&nb[tid * LSTR + cg * 4]) = pk;
            }
        }
    }
    // epilogue: wave w owns vox0 + w*64 + t*16 + r
#pragma unroll
    for (int t = 0; t < 4; ++t) {
        int vox = vox0 + w * 64 + t * 16 + r;
        if (vox < NVOX) {
            float* o = P + ((size_t)bt * NVOX + vox) * CG + q * 4;
#pragma unroll
            for (int gt = 0; gt < 3; ++gt)
                *reinterpret_cast<v4f*>(o + gt * 16) = acc[t][gt];
        }
    }
}

// ---------------------------------------------------------------------------
// Pass 4: trilinear gather from P + bias -> occ_to_gs output.
// ---------------------------------------------------------------------------
__global__ __launch_bounds__(256) void k_gather(
    const float* __restrict__ pts, const float* __restrict__ P,
    const float* __restrict__ bo2g, float* __restrict__ out1)
{
    int idx = blockIdx.x * 256 + threadIdx.x;     // (pn)*CG + g
    int g  = idx % CG;
    int pn = idx / CG;
    int bt = pn / NPT;
    float x = pts[pn * 3 + 0];
    float y = pts[pn * 3 + 1];
    float z = pts[pn * 3 + 2];
    float gx = (x - GMX) / 80.0f * 2.0f - 1.0f;
    float gy = (y - GMY) / 80.0f * 2.0f - 1.0f;
    float gz = (z - GMZ) / 8.0f  * 2.0f - 1.0f;
    float px = ((gx + 1.0f) * (float)NXc - 1.0f) * 0.5f;
    float py = ((gy + 1.0f) * (float)NYc - 1.0f) * 0.5f;
    float pz = ((gz + 1.0f) * (float)NZc - 1.0f) * 0.5f;
    float fx = floorf(px), fy = floorf(py), fz = floorf(pz);
    float rx = px - fx, ry = py - fy, rz = pz - fz;
    int x0 = (int)fx, y0 = (int)fy, z0 = (int)fz;
    float acc = bo2g[g];
    const float* Pb = P + (size_t)bt * NVOX * CG;
#pragma unroll
    for (int dz = 0; dz <= 1; ++dz) {
        int zi = z0 + dz;
        if (zi < 0 || zi >= NZc) continue;
        float wz = dz ? rz : 1.0f - rz;
#pragma unroll
        for (int dy = 0; dy <= 1; ++dy) {
            int yi = y0 + dy;
            if (yi < 0 || yi >= NYc) continue;
            float wy = dy ? ry : 1.0f - ry;
#pragma unroll
            for (int dx = 0; dx <= 1; ++dx) {
                int xi = x0 + dx;
                if (xi < 0 || xi >= NXc) continue;
                float wx = dx ? rx : 1.0f - rx;
                float w = (wx * wy) * wz;
                int lin = zi * (NYc * NXc) + yi * NXc + xi;
                acc = fmaf(w, Pb[(size_t)lin * CG + g], acc);
            }
        }
    }
    out1[idx] = acc;
}

// ---------------------------------------------------------------------------
// Pass 5: sparse GEMM — compact256[slot][256] = mean[slot][48] @ Wg2o + b.
// ---------------------------------------------------------------------------
__global__ __launch_bounds__(256) void k_gemm(
    const float* __restrict__ compactM, const float* __restrict__ cnt,
    const int* __restrict__ list, const int* __restrict__ noccp,
    const float* __restrict__ Wg2o, const float* __restrict__ bg2o,
    float* __restrict__ compact256)
{
    int nocc = *noccp;
    int s0 = blockIdx.x * 32;
    if (s0 >= nocc) return;                      // uniform per block
    __shared__ float Wl[CG * CO];                // 48 KB, [k][c]
    __shared__ float Ml[32 * CG];                // 6 KB means
    for (int j = threadIdx.x; j < CG * CO; j += 256) Wl[j] = Wg2o[j];
    for (int j = threadIdx.x; j < 32 * CG; j += 256) {
        int v = j / CG, k = j - v * CG;
        int slot = s0 + v;
        float m = 0.f;
        if (slot < nocc) {
            int btvox = list[slot];
            m = compactM[(size_t)slot * CG + k] / cnt[btvox];
        }
        Ml[j] = m;
    }
    __syncthreads();
    int wid = threadIdx.x >> 6, l = threadIdx.x & 63;
    int vb = wid * 8;
    float4 bias = *reinterpret_cast<const float4*>(&bg2o[4 * l]);
    float acc[8][4];
#pragma unroll
    for (int v = 0; v < 8; ++v) {
        acc[v][0] = bias.x; acc[v][1] = bias.y; acc[v][2] = bias.z; acc[v][3] = bias.w;
    }
    for (int k = 0; k < CG; k += 4) {
        float4 w0 = *reinterpret_cast<const float4*>(&Wl[(k + 0) * CO + 4 * l]);
        float4 w1 = *reinterpret_cast<const float4*>(&Wl[(k + 1) * CO + 4 * l]);
        float4 w2 = *reinterpret_cast<const float4*>(&Wl[(k + 2) * CO + 4 * l]);
        float4 w3 = *reinterpret_cast<const float4*>(&Wl[(k + 3) * CO + 4 * l]);
#pragma unroll
        for (int v = 0; v < 8; ++v) {
            float4 m4 = *reinterpret_cast<const float4*>(&Ml[(vb + v) * CG + k]);
            acc[v][0] = fmaf(m4.x, w0.x, acc[v][0]);
            acc[v][1] = fmaf(m4.x, w0.y, acc[v][1]);
            acc[v][2] = fmaf(m4.x, w0.z, acc[v][2]);
            acc[v][3] = fmaf(m4.x, w0.w, acc[v][3]);
            acc[v][0] = fmaf(m4.y, w1.x, acc[v][0]);
            acc[v][1] = fmaf(m4.y, w1.y, acc[v][1]);
            acc[v][2] = fmaf(m4.y, w1.z, acc[v][2]);
            acc[v][3] = fmaf(m4.y, w1.w, acc[v][3]);
            acc[v][0] = fmaf(m4.z, w2.x, acc[v][0]);
            acc[v][1] = fmaf(m4.z, w2.y, acc[v][1]);
            acc[v][2] = fmaf(m4.z, w2.z, acc[v][2]);
            acc[v][3] = fmaf(m4.z, w2.w, acc[v][3]);
            acc[v][0] = fmaf(m4.w, w3.x, acc[v][0]);
            acc[v][1] = fmaf(m4.w, w3.y, acc[v][1]);
            acc[v][2] = fmaf(m4.w, w3.z, acc[v][2]);
            acc[v][3] = fmaf(m4.w, w3.w, acc[v][3]);
        }
    }
#pragma unroll
    for (int v = 0; v < 8; ++v) {
        int slot = s0 + vb + v;
        if (slot < nocc) {
            float4 rr; rr.x = acc[v][0]; rr.y = acc[v][1]; rr.z = acc[v][2]; rr.w = acc[v][3];
            *reinterpret_cast<float4*>(&compact256[(size_t)slot * CO + 4 * l]) = rr;
        }
    }
}

// ---------------------------------------------------------------------------
// Pass 6: dense writer. Thread -> 4 consecutive vox; loop 32 channels.
// ---------------------------------------------------------------------------
__global__ __launch_bounds__(256) void k_writer(
    const int* __restrict__ invmap, const float* __restrict__ compact256,
    float* __restrict__ out0)
{
    int bt = blockIdx.z;
    int c0 = blockIdx.y * 32;
    int v0 = blockIdx.x * 1024 + threadIdx.x * 4;
    if (v0 >= NVOX) return;
    int4 sp = *reinterpret_cast<const int4*>(&invmap[bt * NVOX + v0]);
    const float* r0 = compact256 + (size_t)(sp.x - 1) * CO;
    const float* r1 = compact256 + (size_t)(sp.y - 1) * CO;
    const float* r2 = compact256 + (size_t)(sp.z - 1) * CO;
    const float* r3 = compact256 + (size_t)(sp.w - 1) * CO;
    float* ob = out0 + (size_t)bt * CO * NVOX + (size_t)c0 * NVOX + v0;
#pragma unroll 4
    for (int ci = 0; ci < 32; ++ci) {
        int c = c0 + ci;
        v4f val;
        val.x = sp.x ? r0[c] : 0.f;
        val.y = sp.y ? r1[c] : 0.f;
        val.z = sp.z ? r2[c] : 0.f;
        val.w = sp.w ? r3[c] : 0.f;
        __builtin_nontemporal_store(val, reinterpret_cast<v4f*>(ob + (size_t)ci * NVOX));
    }
}

// ---------------------------------------------------------------------------
extern "C" void kernel_launch(void* const* d_in, const int* in_sizes, int n_in,
                              void* d_out, int out_size, void* d_ws, size_t ws_size,
                              hipStream_t stream)
{
    const float* centers = (const float*)d_in[0];
    const float* feats   = (const float*)d_in[1];
    const float* occ     = (const float*)d_in[2];
    const float* Wg2o    = (const float*)d_in[3];
    const float* bg2o    = (const float*)d_in[4];
    const float* Wo2g    = (const float*)d_in[5];
    const float* bo2g    = (const float*)d_in[6];

    float* out  = (float*)d_out;
    float* out0 = out;                                   // [BT][CO][NVOX]
    float* out1 = out + (size_t)BT * CO * NVOX;          // [BT][NPT][CG]
    // f32 P in tail of out0: written by volproj, read by gather, overwritten
    // by writer (stream-ordered).
    float* P    = out0 + (size_t)BT * CO * NVOX - (size_t)BT * NVOX * CG;
    // Packed bf16 W fragments at head of out1 (24 KB): written by k_init,
    // read by k_volproj, then fully overwritten by k_gather.
    short* wp   = (short*)out1;

    // ws layout: zeroed region first (cnt, nocc, invmap, compactM), then rest.
    char* w = (char*)d_ws;
    float* cnt       = (float*)w;                 w += (size_t)BT * NVOX * 4;       // 800000
    int*   nocc      = (int*)w;                   w += 256;
    int*   invmap    = (int*)w;                   w += (size_t)BT * NVOX * 4;       // 800000
    float* compactM  = (float*)w;                 w += (size_t)MAXS * CG * 4;       // 6488064
    size_t zbytes = (size_t)BT * NVOX * 4 + 256 + (size_t)BT * NVOX * 4
                  + (size_t)MAXS * CG * 4;       // 8,088,320 (16B-divisible)
    int*   ptvox     = (int*)w;                   w += (size_t)NPTS * 4;            // 135168
    int*   list      = (int*)w;                   w += (size_t)MAXS * 4;            // 135168
    float* compact256 = (float*)w;               // MAXS*CO*4 = 34603008

    k_init<<<1025, 256, 0, stream>>>((v4f*)d_ws, (int)(zbytes / 16), Wo2g, wp);
    k_count<<<NPTS / 256, 256, 0, stream>>>(centers, cnt, nocc, invmap, ptvox, list);
    k_scatterM<<<NPTS * CG / 256, 256, 0, stream>>>(feats, ptvox, invmap, compactM);
    k_volproj<<<BT * NTB, 256, 0, stream>>>(occ, wp, P);
    k_gather<<<NPTS * CG / 256, 256, 0, stream>>>(centers, P, bo2g, out1);
    k_gemm<<<(MAXS + 31) / 32, 256, 0, stream>>>(compactM, cnt, list, nocc, Wg2o, bg2o, compact256);
    k_writer<<<dim3((NVOX + 1023) / 1024, 8, BT), 256, 0, stream>>>(invmap, compact256, out0);
}

// Round 12
// 158.480 us; speedup vs baseline: 1.2943x; 1.1048x over previous
//
#include <hip/hip_runtime.h>
#include <hip/hip_bf16.h>

typedef float v4f __attribute__((ext_vector_type(4)));
typedef short bfrag8 __attribute__((ext_vector_type(8)));

// Problem constants (match reference)
constexpr int NXc = 100, NYc = 100, NZc = 10;
constexpr int NVOX = NZc * NYc * NXc;      // 100000
constexpr int CO = 256, CG = 48;
constexpr int BT = 2;
constexpr int NPT = 6 * 32 * 88;           // 16896 points per bt
constexpr int NPTS = BT * NPT;             // 33792
constexpr int MAXS = NPTS;                 // max occupied voxels
constexpr int NW64 = (NVOX + 63) / 64;     // 1563 64-vox wave-groups per bt
constexpr int NB_VP = (BT * NW64 + 3) / 4; // 782 volproj blocks
constexpr int NB_SC = NPTS * CG / 256;     // 6336 scatter blocks
constexpr int NB_WV = (NVOX + 1023) / 1024;// 98 vox-groups for writer
constexpr int NB_WR = NB_WV * 8 * BT;      // 1568 writer blocks
constexpr int NB_GA = NPTS * CG / 256;     // 6336 gather blocks
constexpr float GMX = -40.0f, GMY = -40.0f, GMZ = -2.0f;
constexpr float VOXEL = 0.8f;

static __device__ __forceinline__ short f2bf(float f) {
    __hip_bfloat16 h = __float2bfloat16(f);
    return __builtin_bit_cast(short, h);
}

// ---------------------------------------------------------------------------
// Pass 0: blocks 0..1023 zero the scatter scratch; block 1024 packs Wo2g^T
// into bf16 MFMA A-fragments (k = s*32 + (l>>4)*8 + j, g = gt*16 + (l&15)).
// ---------------------------------------------------------------------------
__global__ __launch_bounds__(256) void k_init(
    v4f* __restrict__ p, int n16,
    const float* __restrict__ Wo2g, short* __restrict__ wp)
{
    if (blockIdx.x < 1024) {
        v4f z = {0.f, 0.f, 0.f, 0.f};
        for (int i = blockIdx.x * 256 + threadIdx.x; i < n16; i += 1024 * 256)
            p[i] = z;
    } else {
        for (int e = threadIdx.x; e < 8 * 3 * 64 * 8; e += 256) {
            int j  = e & 7;
            int l  = (e >> 3) & 63;
            int ft = e >> 9;                      // s*3 + gt
            int s  = ft / 3, gt = ft - 3 * s;
            int k  = s * 32 + (l >> 4) * 8 + j;
            int g  = gt * 16 + (l & 15);
            wp[e] = f2bf(Wo2g[k * CG + g]);
        }
    }
}

// ---------------------------------------------------------------------------
// Pass 1: per point -> voxel; count + assign compact slots + slot list.
// ---------------------------------------------------------------------------
__global__ __launch_bounds__(256) void k_count(
    const float* __restrict__ pts, float* __restrict__ cnt,
    int* __restrict__ nocc, int* __restrict__ invmap, int* __restrict__ ptvox,
    int* __restrict__ list)
{
    int pn = blockIdx.x * 256 + threadIdx.x;      // < NPTS (exact grid)
    float x = pts[pn * 3 + 0];
    float y = pts[pn * 3 + 1];
    float z = pts[pn * 3 + 2];
    int ix = (int)floorf((x - GMX) / VOXEL);
    int iy = (int)floorf((y - GMY) / VOXEL);
    int iz = (int)floorf((z - GMZ) / VOXEL);
    bool valid = (ix >= 0 && ix < NXc && iy >= 0 && iy < NYc && iz >= 0 && iz < NZc);
    if (!valid) { ptvox[pn] = -1; return; }
    int bt = pn / NPT;
    int btvox = bt * NVOX + iz * (NYc * NXc) + iy * NXc + ix;
    ptvox[pn] = btvox;
    float old = atomicAdd(&cnt[btvox], 1.0f);
    if (old == 0.0f) {
        int s = atomicAdd(nocc, 1);
        invmap[btvox] = s + 1;                    // 0 = empty
        list[s] = btvox;
    }
}

// ---------------------------------------------------------------------------
// megaA: blocks [0,NB_VP) = volproj (MFMA, R10 form); rest = scatterM.
// Independent: volproj reads occ/wp -> P(ws); scatterM reads feats/ptvox ->
// compactM. Overlaps BW/MFMA-bound with atomic-bound work.
// ---------------------------------------------------------------------------
__global__ __launch_bounds__(256) void k_megaA(
    const float* __restrict__ occ, const short* __restrict__ wp,
    float* __restrict__ P,
    const float* __restrict__ feats, const int* __restrict__ ptvox,
    const int* __restrict__ invmap, float* __restrict__ compactM)
{
    if (blockIdx.x < NB_VP) {
        // ---- volproj ----
        int gwid = (blockIdx.x * 256 + threadIdx.x) >> 6;
        if (gwid >= BT * NW64) return;
        int l = threadIdx.x & 63;
        int q = l >> 4, r = l & 15;
        const bfrag8* wf = reinterpret_cast<const bfrag8*>(wp);
        bfrag8 wfr[8][3];
#pragma unroll
        for (int s = 0; s < 8; ++s)
#pragma unroll
            for (int gt = 0; gt < 3; ++gt)
                wfr[s][gt] = wf[(s * 3 + gt) * 64 + l];
        int bt = gwid / NW64;
        int vox0 = (gwid - bt * NW64) * 64;
        int vbase = vox0 + 4 * r;
        int vload = vbase > NVOX - 4 ? NVOX - 4 : vbase;
        const float* b0 = occ + (size_t)bt * CO * NVOX + (size_t)q * 8 * NVOX + vload;
        v4f acc[4][3];
#pragma unroll
        for (int t = 0; t < 4; ++t)
#pragma unroll
            for (int gt = 0; gt < 3; ++gt)
                acc[t][gt] = v4f{0.f, 0.f, 0.f, 0.f};
#pragma unroll
        for (int s = 0; s < 8; ++s) {
            v4f vj[8];
#pragma unroll
            for (int j = 0; j < 8; ++j)
                vj[j] = *reinterpret_cast<const v4f*>(b0 + (size_t)(s * 32 + j) * NVOX);
            bfrag8 bf[4];
#pragma unroll
            for (int t = 0; t < 4; ++t)
#pragma unroll
                for (int j = 0; j < 8; ++j)
                    bf[t][j] = f2bf(vj[j][t]);
#pragma unroll
            for (int t = 0; t < 4; ++t)
#pragma unroll
                for (int gt = 0; gt < 3; ++gt)
                    acc[t][gt] = __builtin_amdgcn_mfma_f32_16x16x32_bf16(
                        wfr[s][gt], bf[t], acc[t][gt], 0, 0, 0);
        }
        float* o = P + ((size_t)bt * NVOX + vbase) * CG + q * 4;
#pragma unroll
        for (int t = 0; t < 4; ++t) {
            if (vbase + t < NVOX) {
#pragma unroll
                for (int gt = 0; gt < 3; ++gt)
                    *reinterpret_cast<v4f*>(o + t * CG + gt * 16) = acc[t][gt];
            }
        }
    } else {
        // ---- scatterM ----
        int idx = (blockIdx.x - NB_VP) * 256 + threadIdx.x;  // (pn)*CG + k
        int k  = idx % CG;
        int pn = idx / CG;
        int bv = ptvox[pn];
        if (bv < 0) return;
        int slot = invmap[bv] - 1;
        atomicAdd(&compactM[(size_t)slot * CG + k], feats[idx]);
    }
}

// ---------------------------------------------------------------------------
// Pass 5: sparse GEMM — compact256[slot][256] = mean[slot][48] @ Wg2o + b.
// ---------------------------------------------------------------------------
__global__ __launch_bounds__(256) void k_gemm(
    const float* __restrict__ compactM, const float* __restrict__ cnt,
    const int* __restrict__ list, const int* __restrict__ noccp,
    const float* __restrict__ Wg2o, const float* __restrict__ bg2o,
    float* __restrict__ compact256)
{
    int nocc = *noccp;
    int s0 = blockIdx.x * 32;
    if (s0 >= nocc) return;                      // uniform per block
    __shared__ float Wl[CG * CO];                // 48 KB, [k][c]
    __shared__ float Ml[32 * CG];                // 6 KB means
    for (int j = threadIdx.x; j < CG * CO; j += 256) Wl[j] = Wg2o[j];
    for (int j = threadIdx.x; j < 32 * CG; j += 256) {
        int v = j / CG, k = j - v * CG;
        int slot = s0 + v;
        float m = 0.f;
        if (slot < nocc) {
            int btvox = list[slot];
            m = compactM[(size_t)slot * CG + k] / cnt[btvox];
        }
        Ml[j] = m;
    }
    __syncthreads();
    int wid = threadIdx.x >> 6, l = threadIdx.x & 63;
    int vb = wid * 8;
    float4 bias = *reinterpret_cast<const float4*>(&bg2o[4 * l]);
    float acc[8][4];
#pragma unroll
    for (int v = 0; v < 8; ++v) {
        acc[v][0] = bias.x; acc[v][1] = bias.y; acc[v][2] = bias.z; acc[v][3] = bias.w;
    }
    for (int k = 0; k < CG; k += 4) {
        float4 w0 = *reinterpret_cast<const float4*>(&Wl[(k + 0) * CO + 4 * l]);
        float4 w1 = *reinterpret_cast<const float4*>(&Wl[(k + 1) * CO + 4 * l]);
        float4 w2 = *reinterpret_cast<const float4*>(&Wl[(k + 2) * CO + 4 * l]);
        float4 w3 = *reinterpret_cast<const float4*>(&Wl[(k + 3) * CO + 4 * l]);
#pragma unroll
        for (int v = 0; v < 8; ++v) {
            float4 m4 = *reinterpret_cast<const float4*>(&Ml[(vb + v) * CG + k]);
            acc[v][0] = fmaf(m4.x, w0.x, acc[v][0]);
            acc[v][1] = fmaf(m4.x, w0.y, acc[v][1]);
            acc[v][2] = fmaf(m4.x, w0.z, acc[v][2]);
            acc[v][3] = fmaf(m4.x, w0.w, acc[v][3]);
            acc[v][0] = fmaf(m4.y, w1.x, acc[v][0]);
            acc[v][1] = fmaf(m4.y, w1.y, acc[v][1]);
            acc[v][2] = fmaf(m4.y, w1.z, acc[v][2]);
            acc[v][3] = fmaf(m4.y, w1.w, acc[v][3]);
            acc[v][0] = fmaf(m4.z, w2.x, acc[v][0]);
            acc[v][1] = fmaf(m4.z, w2.y, acc[v][1]);
            acc[v][2] = fmaf(m4.z, w2.z, acc[v][2]);
            acc[v][3] = fmaf(m4.z, w2.w, acc[v][3]);
            acc[v][0] = fmaf(m4.w, w3.x, acc[v][0]);
            acc[v][1] = fmaf(m4.w, w3.y, acc[v][1]);
            acc[v][2] = fmaf(m4.w, w3.z, acc[v][2]);
            acc[v][3] = fmaf(m4.w, w3.w, acc[v][3]);
        }
    }
#pragma unroll
    for (int v = 0; v < 8; ++v) {
        int slot = s0 + vb + v;
        if (slot < nocc) {
            float4 rr; rr.x = acc[v][0]; rr.y = acc[v][1]; rr.z = acc[v][2]; rr.w = acc[v][3];
            *reinterpret_cast<float4*>(&compact256[(size_t)slot * CO + 4 * l]) = rr;
        }
    }
}

// ---------------------------------------------------------------------------
// megaB: blocks [0,NB_WR) = writer (LDS-transposed, vector row loads);
// rest = gather. writer reads invmap/compact256 -> out0; gather reads
// P(ws)/centers -> out1. Write-stream overlaps read-gather.
// ---------------------------------------------------------------------------
__global__ __launch_bounds__(256) void k_megaB(
    const int* __restrict__ invmap, const float* __restrict__ compact256,
    float* __restrict__ out0,
    const float* __restrict__ pts, const float* __restrict__ P,
    const float* __restrict__ bo2g, float* __restrict__ out1)
{
    __shared__ float ldsT[32][260];               // 33.3 KB, padded
    if (blockIdx.x < NB_WR) {
        // ---- writer ----
        int wbid = blockIdx.x;
        int bt  = wbid / (NB_WV * 8);
        int rem = wbid - bt * (NB_WV * 8);
        int c0  = (rem / NB_WV) * 32;
        int vb  = (rem - (rem / NB_WV) * NB_WV) * 1024;
        int tid = threadIdx.x;
        int w = tid >> 6, l = tid & 63;
        float* ob = out0 + (size_t)bt * CO * NVOX;
#pragma unroll
        for (int sc = 0; sc < 4; ++sc) {
            int vbase = vb + sc * 256;
            int vox = vbase + tid;
            int slot = (vox < NVOX) ? invmap[bt * NVOX + vox] : 0;
            if (slot > 0) {
                const v4f* row = reinterpret_cast<const v4f*>(
                    compact256 + (size_t)(slot - 1) * CO + c0);
#pragma unroll
                for (int cq = 0; cq < 8; ++cq) {
                    v4f d = row[cq];
#pragma unroll
                    for (int i = 0; i < 4; ++i) ldsT[cq * 4 + i][tid] = d[i];
                }
            } else {
#pragma unroll
                for (int c = 0; c < 32; ++c) ldsT[c][tid] = 0.f;
            }
            __syncthreads();
#pragma unroll
            for (int u = 0; u < 8; ++u) {
                int ci = u * 4 + w;
                int vq = 4 * l;
                int vv = vbase + vq;
                if (vv < NVOX) {
                    v4f val = *reinterpret_cast<const v4f*>(&ldsT[ci][vq]);
                    __builtin_nontemporal_store(val,
                        reinterpret_cast<v4f*>(ob + (size_t)(c0 + ci) * NVOX + vv));
                }
            }
            if (sc < 3) __syncthreads();
        }
    } else {
        // ---- gather ----
        int idx = (blockIdx.x - NB_WR) * 256 + threadIdx.x;  // (pn)*CG + g
        int g  = idx % CG;
        int pn = idx / CG;
        int bt = pn / NPT;
        float x = pts[pn * 3 + 0];
        float y = pts[pn * 3 + 1];
        float z = pts[pn * 3 + 2];
        float gx = (x - GMX) / 80.0f * 2.0f - 1.0f;
        float gy = (y - GMY) / 80.0f * 2.0f - 1.0f;
        float gz = (z - GMZ) / 8.0f  * 2.0f - 1.0f;
        float px = ((gx + 1.0f) * (float)NXc - 1.0f) * 0.5f;
        float py = ((gy + 1.0f) * (float)NYc - 1.0f) * 0.5f;
        float pz = ((gz + 1.0f) * (float)NZc - 1.0f) * 0.5f;
        float fx = floorf(px), fy = floorf(py), fz = floorf(pz);
        float rx = px - fx, ry = py - fy, rz = pz - fz;
        int x0 = (int)fx, y0 = (int)fy, z0 = (int)fz;
        float acc = bo2g[g];
        const float* Pb = P + (size_t)bt * NVOX * CG;
#pragma unroll
        for (int dz = 0; dz <= 1; ++dz) {
            int zi = z0 + dz;
            if (zi < 0 || zi >= NZc) continue;
            float wz = dz ? rz : 1.0f - rz;
#pragma unroll
            for (int dy = 0; dy <= 1; ++dy) {
                int yi = y0 + dy;
                if (yi < 0 || yi >= NYc) continue;
                float wy = dy ? ry : 1.0f - ry;
#pragma unroll
                for (int dx = 0; dx <= 1; ++dx) {
                    int xi = x0 + dx;
                    if (xi < 0 || xi >= NXc) continue;
                    float wx = dx ? rx : 1.0f - rx;
                    float w = (wx * wy) * wz;
                    int lin = zi * (NYc * NXc) + yi * NXc + xi;
                    acc = fmaf(w, Pb[(size_t)lin * CG + g], acc);
                }
            }
        }
        out1[idx] = acc;
    }
}

// ---------------------------------------------------------------------------
extern "C" void kernel_launch(void* const* d_in, const int* in_sizes, int n_in,
                              void* d_out, int out_size, void* d_ws, size_t ws_size,
                              hipStream_t stream)
{
    const float* centers = (const float*)d_in[0];
    const float* feats   = (const float*)d_in[1];
    const float* occ     = (const float*)d_in[2];
    const float* Wg2o    = (const float*)d_in[3];
    const float* bg2o    = (const float*)d_in[4];
    const float* Wo2g    = (const float*)d_in[5];
    const float* bo2g    = (const float*)d_in[6];

    float* out  = (float*)d_out;
    float* out0 = out;                                   // [BT][CO][NVOX]
    float* out1 = out + (size_t)BT * CO * NVOX;          // [BT][NPT][CG]
    // Packed bf16 W fragments at head of out1 (24 KB): written by k_init,
    // consumed by megaA(volproj), then overwritten by megaB(gather).
    short* wp   = (short*)out1;

    // ws layout: zeroed region first (cnt, nocc, invmap, compactM), then rest.
    // P now lives in ws (not out0) so megaB's writer can run concurrently
    // with gather.
    char* w = (char*)d_ws;
    float* cnt       = (float*)w;                 w += (size_t)BT * NVOX * 4;       // 800000
    int*   nocc      = (int*)w;                   w += 256;
    int*   invmap    = (int*)w;                   w += (size_t)BT * NVOX * 4;       // 800000
    float* compactM  = (float*)w;                 w += (size_t)MAXS * CG * 4;       // 6488064
    size_t zbytes = (size_t)BT * NVOX * 4 + 256 + (size_t)BT * NVOX * 4
                  + (size_t)MAXS * CG * 4;       // 8,088,320 (16B-divisible)
    int*   ptvox     = (int*)w;                   w += (size_t)NPTS * 4;            // 135168
    int*   list      = (int*)w;                   w += (size_t)MAXS * 4;            // 135168
    float* compact256= (float*)w;                 w += (size_t)MAXS * CO * 4;       // 34603008
    float* P         = (float*)w;                 // BT*NVOX*CG*4 = 38400000

    k_init<<<1025, 256, 0, stream>>>((v4f*)d_ws, (int)(zbytes / 16), Wo2g, wp);
    k_count<<<NPTS / 256, 256, 0, stream>>>(centers, cnt, nocc, invmap, ptvox, list);
    k_megaA<<<NB_VP + NB_SC, 256, 0, stream>>>(occ, wp, P, feats, ptvox, invmap, compactM);
    k_gemm<<<(MAXS + 31) / 32, 256, 0, stream>>>(compactM, cnt, list, nocc, Wg2o, bg2o, compact256);
    k_megaB<<<NB_WR + NB_GA, 256, 0, stream>>>(invmap, compact256, out0, centers, P, bo2g, out1);
}

// Round 13
// 153.831 us; speedup vs baseline: 1.3334x; 1.0302x over previous
//
#include <hip/hip_runtime.h>
#include <hip/hip_bf16.h>

typedef float v4f __attribute__((ext_vector_type(4)));
typedef short bfrag8 __attribute__((ext_vector_type(8)));

// Problem constants (match reference)
constexpr int NXc = 100, NYc = 100, NZc = 10;
constexpr int NVOX = NZc * NYc * NXc;      // 100000
constexpr int CO = 256, CG = 48;
constexpr int BT = 2;
constexpr int NPT = 6 * 32 * 88;           // 16896 points per bt
constexpr int NPTS = BT * NPT;             // 33792
constexpr int MAXS = NPTS;                 // max occupied voxels
constexpr int NW64 = (NVOX + 63) / 64;     // 1563 64-vox wave-groups per bt
constexpr int NB_VP = (BT * NW64 + 3) / 4; // 782 volproj blocks
constexpr int NB_SC = NPTS * CG / 256;     // 6336 scatter blocks
constexpr int NB_WV = (NVOX + 1023) / 1024;// 98 vox-groups for writer
constexpr int NB_WR = NB_WV * 8 * BT;      // 1568 writer blocks
constexpr int NB_GA = NPTS * CG / 256;     // 6336 gather blocks
constexpr float GMX = -40.0f, GMY = -40.0f, GMZ = -2.0f;
constexpr float VOXEL = 0.8f;

static __device__ __forceinline__ short f2bf(float f) {
    __hip_bfloat16 h = __float2bfloat16(f);
    return __builtin_bit_cast(short, h);
}

// ---------------------------------------------------------------------------
// Pass 0: blocks 0..1023 zero the scatter scratch; block 1024 packs Wo2g^T
// into bf16 MFMA A-fragments (k = s*32 + (l>>4)*8 + j, g = gt*16 + (l&15)).
// ---------------------------------------------------------------------------
__global__ __launch_bounds__(256) void k_init(
    v4f* __restrict__ p, int n16,
    const float* __restrict__ Wo2g, short* __restrict__ wp)
{
    if (blockIdx.x < 1024) {
        v4f z = {0.f, 0.f, 0.f, 0.f};
        for (int i = blockIdx.x * 256 + threadIdx.x; i < n16; i += 1024 * 256)
            p[i] = z;
    } else {
        for (int e = threadIdx.x; e < 8 * 3 * 64 * 8; e += 256) {
            int j  = e & 7;
            int l  = (e >> 3) & 63;
            int ft = e >> 9;                      // s*3 + gt
            int s  = ft / 3, gt = ft - 3 * s;
            int k  = s * 32 + (l >> 4) * 8 + j;
            int g  = gt * 16 + (l & 15);
            wp[e] = f2bf(Wo2g[k * CG + g]);
        }
    }
}

// ---------------------------------------------------------------------------
// Pass 1: per point -> voxel; count + assign compact slots + slot list.
// ---------------------------------------------------------------------------
__global__ __launch_bounds__(256) void k_count(
    const float* __restrict__ pts, float* __restrict__ cnt,
    int* __restrict__ nocc, int* __restrict__ invmap, int* __restrict__ ptvox,
    int* __restrict__ list)
{
    int pn = blockIdx.x * 256 + threadIdx.x;      // < NPTS (exact grid)
    float x = pts[pn * 3 + 0];
    float y = pts[pn * 3 + 1];
    float z = pts[pn * 3 + 2];
    int ix = (int)floorf((x - GMX) / VOXEL);
    int iy = (int)floorf((y - GMY) / VOXEL);
    int iz = (int)floorf((z - GMZ) / VOXEL);
    bool valid = (ix >= 0 && ix < NXc && iy >= 0 && iy < NYc && iz >= 0 && iz < NZc);
    if (!valid) { ptvox[pn] = -1; return; }
    int bt = pn / NPT;
    int btvox = bt * NVOX + iz * (NYc * NXc) + iy * NXc + ix;
    ptvox[pn] = btvox;
    float old = atomicAdd(&cnt[btvox], 1.0f);
    if (old == 0.0f) {
        int s = atomicAdd(nocc, 1);
        invmap[btvox] = s + 1;                    // 0 = empty
        list[s] = btvox;
    }
}

// ---------------------------------------------------------------------------
// megaA: every 9th block = volproj (782), rest = scatterM (6336) —
// INTERLEAVED so every CU hosts both roles concurrently (scatter hides in
// volproj's memory-latency gaps instead of running as a serial tail).
// ---------------------------------------------------------------------------
__global__ __launch_bounds__(256) void k_megaA(
    const float* __restrict__ occ, const short* __restrict__ wp,
    float* __restrict__ P,
    const float* __restrict__ feats, const int* __restrict__ ptvox,
    const int* __restrict__ invmap, float* __restrict__ compactM)
{
    int bid = blockIdx.x;
    int vpq = bid / 9;
    bool is_vp = (bid % 9 == 0) && (vpq < NB_VP);
    if (is_vp) {
        // ---- volproj ----
        int gwid = (vpq * 256 + threadIdx.x) >> 6;
        if (gwid >= BT * NW64) return;
        int l = threadIdx.x & 63;
        int q = l >> 4, r = l & 15;
        const bfrag8* wf = reinterpret_cast<const bfrag8*>(wp);
        bfrag8 wfr[8][3];
#pragma unroll
        for (int s = 0; s < 8; ++s)
#pragma unroll
            for (int gt = 0; gt < 3; ++gt)
                wfr[s][gt] = wf[(s * 3 + gt) * 64 + l];
        int bt = gwid / NW64;
        int vox0 = (gwid - bt * NW64) * 64;
        int vbase = vox0 + 4 * r;
        int vload = vbase > NVOX - 4 ? NVOX - 4 : vbase;
        const float* b0 = occ + (size_t)bt * CO * NVOX + (size_t)q * 8 * NVOX + vload;
        v4f acc[4][3];
#pragma unroll
        for (int t = 0; t < 4; ++t)
#pragma unroll
            for (int gt = 0; gt < 3; ++gt)
                acc[t][gt] = v4f{0.f, 0.f, 0.f, 0.f};
#pragma unroll
        for (int s = 0; s < 8; ++s) {
            v4f vj[8];
#pragma unroll
            for (int j = 0; j < 8; ++j)
                vj[j] = *reinterpret_cast<const v4f*>(b0 + (size_t)(s * 32 + j) * NVOX);
            bfrag8 bf[4];
#pragma unroll
            for (int t = 0; t < 4; ++t)
#pragma unroll
                for (int j = 0; j < 8; ++j)
                    bf[t][j] = f2bf(vj[j][t]);
#pragma unroll
            for (int t = 0; t < 4; ++t)
#pragma unroll
                for (int gt = 0; gt < 3; ++gt)
                    acc[t][gt] = __builtin_amdgcn_mfma_f32_16x16x32_bf16(
                        wfr[s][gt], bf[t], acc[t][gt], 0, 0, 0);
        }
        float* o = P + ((size_t)bt * NVOX + vbase) * CG + q * 4;
#pragma unroll
        for (int t = 0; t < 4; ++t) {
            if (vbase + t < NVOX) {
#pragma unroll
                for (int gt = 0; gt < 3; ++gt)
                    *reinterpret_cast<v4f*>(o + t * CG + gt * 16) = acc[t][gt];
            }
        }
    } else {
        // ---- scatterM ----
        int nvp = (bid + 8) / 9; if (nvp > NB_VP) nvp = NB_VP;
        int scid = bid - nvp;
        int idx = scid * 256 + threadIdx.x;       // (pn)*CG + k
        int k  = idx % CG;
        int pn = idx / CG;
        int bv = ptvox[pn];
        if (bv < 0) return;
        int slot = invmap[bv] - 1;
        atomicAdd(&compactM[(size_t)slot * CG + k], feats[idx]);
    }
}

// ---------------------------------------------------------------------------
// Pass 5: sparse GEMM — compact256[slot][256] = mean[slot][48] @ Wg2o + b.
// ---------------------------------------------------------------------------
__global__ __launch_bounds__(256) void k_gemm(
    const float* __restrict__ compactM, const float* __restrict__ cnt,
    const int* __restrict__ list, const int* __restrict__ noccp,
    const float* __restrict__ Wg2o, const float* __restrict__ bg2o,
    float* __restrict__ compact256)
{
    int nocc = *noccp;
    int s0 = blockIdx.x * 32;
    if (s0 >= nocc) return;                      // uniform per block
    __shared__ float Wl[CG * CO];                // 48 KB, [k][c]
    __shared__ float Ml[32 * CG];                // 6 KB means
    for (int j = threadIdx.x; j < CG * CO; j += 256) Wl[j] = Wg2o[j];
    for (int j = threadIdx.x; j < 32 * CG; j += 256) {
        int v = j / CG, k = j - v * CG;
        int slot = s0 + v;
        float m = 0.f;
        if (slot < nocc) {
            int btvox = list[slot];
            m = compactM[(size_t)slot * CG + k] / cnt[btvox];
        }
        Ml[j] = m;
    }
    __syncthreads();
    int wid = threadIdx.x >> 6, l = threadIdx.x & 63;
    int vb = wid * 8;
    float4 bias = *reinterpret_cast<const float4*>(&bg2o[4 * l]);
    float acc[8][4];
#pragma unroll
    for (int v = 0; v < 8; ++v) {
        acc[v][0] = bias.x; acc[v][1] = bias.y; acc[v][2] = bias.z; acc[v][3] = bias.w;
    }
    for (int k = 0; k < CG; k += 4) {
        float4 w0 = *reinterpret_cast<const float4*>(&Wl[(k + 0) * CO + 4 * l]);
        float4 w1 = *reinterpret_cast<const float4*>(&Wl[(k + 1) * CO + 4 * l]);
        float4 w2 = *reinterpret_cast<const float4*>(&Wl[(k + 2) * CO + 4 * l]);
        float4 w3 = *reinterpret_cast<const float4*>(&Wl[(k + 3) * CO + 4 * l]);
#pragma unroll
        for (int v = 0; v < 8; ++v) {
            float4 m4 = *reinterpret_cast<const float4*>(&Ml[(vb + v) * CG + k]);
            acc[v][0] = fmaf(m4.x, w0.x, acc[v][0]);
            acc[v][1] = fmaf(m4.x, w0.y, acc[v][1]);
            acc[v][2] = fmaf(m4.x, w0.z, acc[v][2]);
            acc[v][3] = fmaf(m4.x, w0.w, acc[v][3]);
            acc[v][0] = fmaf(m4.y, w1.x, acc[v][0]);
            acc[v][1] = fmaf(m4.y, w1.y, acc[v][1]);
            acc[v][2] = fmaf(m4.y, w1.z, acc[v][2]);
            acc[v][3] = fmaf(m4.y, w1.w, acc[v][3]);
            acc[v][0] = fmaf(m4.z, w2.x, acc[v][0]);
            acc[v][1] = fmaf(m4.z, w2.y, acc[v][1]);
            acc[v][2] = fmaf(m4.z, w2.z, acc[v][2]);
            acc[v][3] = fmaf(m4.z, w2.w, acc[v][3]);
            acc[v][0] = fmaf(m4.w, w3.x, acc[v][0]);
            acc[v][1] = fmaf(m4.w, w3.y, acc[v][1]);
            acc[v][2] = fmaf(m4.w, w3.z, acc[v][2]);
            acc[v][3] = fmaf(m4.w, w3.w, acc[v][3]);
        }
    }
#pragma unroll
    for (int v = 0; v < 8; ++v) {
        int slot = s0 + vb + v;
        if (slot < nocc) {
            float4 rr; rr.x = acc[v][0]; rr.y = acc[v][1]; rr.z = acc[v][2]; rr.w = acc[v][3];
            *reinterpret_cast<float4*>(&compact256[(size_t)slot * CO + 4 * l]) = rr;
        }
    }
}

// ---------------------------------------------------------------------------
// megaB: every 5th block = writer (1568), rest = gather (6336) — interleaved.
// ---------------------------------------------------------------------------
__global__ __launch_bounds__(256) void k_megaB(
    const int* __restrict__ invmap, const float* __restrict__ compact256,
    float* __restrict__ out0,
    const float* __restrict__ pts, const float* __restrict__ P,
    const float* __restrict__ bo2g, float* __restrict__ out1)
{
    __shared__ float ldsT[32][260];               // 33.3 KB, padded
    int bid = blockIdx.x;
    int wrq = bid / 5;
    bool is_wr = (bid % 5 == 0) && (wrq < NB_WR);
    if (is_wr) {
        // ---- writer ----
        int bt  = wrq / (NB_WV * 8);
        int rem = wrq - bt * (NB_WV * 8);
        int c0  = (rem / NB_WV) * 32;
        int vb  = (rem - (rem / NB_WV) * NB_WV) * 1024;
        int tid = threadIdx.x;
        int w = tid >> 6, l = tid & 63;
        float* ob = out0 + (size_t)bt * CO * NVOX;
#pragma unroll
        for (int sc = 0; sc < 4; ++sc) {
            int vbase = vb + sc * 256;
            int vox = vbase + tid;
            int slot = (vox < NVOX) ? invmap[bt * NVOX + vox] : 0;
            if (slot > 0) {
                const v4f* row = reinterpret_cast<const v4f*>(
                    compact256 + (size_t)(slot - 1) * CO + c0);
#pragma unroll
                for (int cq = 0; cq < 8; ++cq) {
                    v4f d = row[cq];
#pragma unroll
                    for (int i = 0; i < 4; ++i) ldsT[cq * 4 + i][tid] = d[i];
                }
            } else {
#pragma unroll
                for (int c = 0; c < 32; ++c) ldsT[c][tid] = 0.f;
            }
            __syncthreads();
#pragma unroll
            for (int u = 0; u < 8; ++u) {
                int ci = u * 4 + w;
                int vq = 4 * l;
                int vv = vbase + vq;
                if (vv < NVOX) {
                    v4f val = *reinterpret_cast<const v4f*>(&ldsT[ci][vq]);
                    __builtin_nontemporal_store(val,
                        reinterpret_cast<v4f*>(ob + (size_t)(c0 + ci) * NVOX + vv));
                }
            }
            if (sc < 3) __syncthreads();
        }
    } else {
        // ---- gather ----
        int nwr = (bid + 4) / 5; if (nwr > NB_WR) nwr = NB_WR;
        int gaid = bid - nwr;
        int idx = gaid * 256 + threadIdx.x;       // (pn)*CG + g
        int g  = idx % CG;
        int pn = idx / CG;
        int bt = pn / NPT;
        float x = pts[pn * 3 + 0];
        float y = pts[pn * 3 + 1];
        float z = pts[pn * 3 + 2];
        float gx = (x - GMX) / 80.0f * 2.0f - 1.0f;
        float gy = (y - GMY) / 80.0f * 2.0f - 1.0f;
        float gz = (z - GMZ) / 8.0f  * 2.0f - 1.0f;
        float px = ((gx + 1.0f) * (float)NXc - 1.0f) * 0.5f;
        float py = ((gy + 1.0f) * (float)NYc - 1.0f) * 0.5f;
        float pz = ((gz + 1.0f) * (float)NZc - 1.0f) * 0.5f;
        float fx = floorf(px), fy = floorf(py), fz = floorf(pz);
        float rx = px - fx, ry = py - fy, rz = pz - fz;
        int x0 = (int)fx, y0 = (int)fy, z0 = (int)fz;
        float acc = bo2g[g];
        const float* Pb = P + (size_t)bt * NVOX * CG;
#pragma unroll
        for (int dz = 0; dz <= 1; ++dz) {
            int zi = z0 + dz;
            if (zi < 0 || zi >= NZc) continue;
            float wz = dz ? rz : 1.0f - rz;
#pragma unroll
            for (int dy = 0; dy <= 1; ++dy) {
                int yi = y0 + dy;
                if (yi < 0 || yi >= NYc) continue;
                float wy = dy ? ry : 1.0f - ry;
#pragma unroll
                for (int dx = 0; dx <= 1; ++dx) {
                    int xi = x0 + dx;
                    if (xi < 0 || xi >= NXc) continue;
                    float wx = dx ? rx : 1.0f - rx;
                    float w = (wx * wy) * wz;
                    int lin = zi * (NYc * NXc) + yi * NXc + xi;
                    acc = fmaf(w, Pb[(size_t)lin * CG + g], acc);
                }
            }
        }
        out1[idx] = acc;
    }
}

// ---------------------------------------------------------------------------
extern "C" void kernel_launch(void* const* d_in, const int* in_sizes, int n_in,
                              void* d_out, int out_size, void* d_ws, size_t ws_size,
                              hipStream_t stream)
{
    const float* centers = (const float*)d_in[0];
    const float* feats   = (const float*)d_in[1];
    const float* occ     = (const float*)d_in[2];
    const float* Wg2o    = (const float*)d_in[3];
    const float* bg2o    = (const float*)d_in[4];
    const float* Wo2g    = (const float*)d_in[5];
    const float* bo2g    = (const float*)d_in[6];

    float* out  = (float*)d_out;
    float* out0 = out;                                   // [BT][CO][NVOX]
    float* out1 = out + (size_t)BT * CO * NVOX;          // [BT][NPT][CG]
    // Packed bf16 W fragments at head of out1 (24 KB): written by k_init,
    // consumed by megaA(volproj), then overwritten by megaB(gather).
    short* wp   = (short*)out1;

    // ws layout: zeroed region first (cnt, nocc, invmap, compactM), then rest.
    char* w = (char*)d_ws;
    float* cnt       = (float*)w;                 w += (size_t)BT * NVOX * 4;       // 800000
    int*   nocc      = (int*)w;                   w += 256;
    int*   invmap    = (int*)w;                   w += (size_t)BT * NVOX * 4;       // 800000
    float* compactM  = (float*)w;                 w += (size_t)MAXS * CG * 4;       // 6488064
    size_t zbytes = (size_t)BT * NVOX * 4 + 256 + (size_t)BT * NVOX * 4
                  + (size_t)MAXS * CG * 4;       // 8,088,320 (16B-divisible)
    int*   ptvox     = (int*)w;                   w += (size_t)NPTS * 4;            // 135168
    int*   list      = (int*)w;                   w += (size_t)MAXS * 4;            // 135168
    float* compact256= (float*)w;                 w += (size_t)MAXS * CO * 4;       // 34603008
    float* P         = (float*)w;                 // BT*NVOX*CG*4 = 38400000

    k_init<<<1025, 256, 0, stream>>>((v4f*)d_ws, (int)(zbytes / 16), Wo2g, wp);
    k_count<<<NPTS / 256, 256, 0, stream>>>(centers, cnt, nocc, invmap, ptvox, list);
    k_megaA<<<NB_VP + NB_SC, 256, 0, stream>>>(occ, wp, P, feats, ptvox, invmap, compactM);
    k_gemm<<<(MAXS + 31) / 32, 256, 0, stream>>>(compactM, cnt, list, nocc, Wg2o, bg2o, compact256);
    k_megaB<<<NB_WR + NB_GA, 256, 0, stream>>>(invmap, compact256, out0, centers, P, bo2g, out1);
}

// Round 14
// 144.920 us; speedup vs baseline: 1.4154x; 1.0615x over previous
//
#include <hip/hip_runtime.h>
#include <hip/hip_bf16.h>

typedef float v4f __attribute__((ext_vector_type(4)));
typedef short v4s __attribute__((ext_vector_type(4)));
typedef short bfrag8 __attribute__((ext_vector_type(8)));

// Problem constants (match reference)
constexpr int NXc = 100, NYc = 100, NZc = 10;
constexpr int NVOX = NZc * NYc * NXc;      // 100000
constexpr int CO = 256, CG = 48;
constexpr int BT = 2;
constexpr int NPT = 6 * 32 * 88;           // 16896 points per bt
constexpr int NPTS = BT * NPT;             // 33792
constexpr int MAXS = NPTS;                 // max occupied voxels
constexpr int NW64 = (NVOX + 63) / 64;     // 1563 64-vox wave-groups per bt
constexpr int NB_VP = (BT * NW64 + 3) / 4; // 782 volproj blocks
constexpr int NB_SC = NPTS * CG / 256;     // 6336 scatter blocks
constexpr int NB_WV = (NVOX + 1023) / 1024;// 98 vox-groups for writer
constexpr int NB_WR = NB_WV * 8 * BT;      // 1568 writer blocks
constexpr int NB_GA = NPTS * CG / 256;     // 6336 gather blocks
constexpr float GMX = -40.0f, GMY = -40.0f, GMZ = -2.0f;
constexpr float VOXEL = 0.8f;

static __device__ __forceinline__ short f2bf(float f) {
    __hip_bfloat16 h = __float2bfloat16(f);
    return __builtin_bit_cast(short, h);
}
static __device__ __forceinline__ float bf2f(unsigned short u) {
    unsigned v = (unsigned)u << 16;
    return __builtin_bit_cast(float, v);
}

// ---------------------------------------------------------------------------
// Pass 0: blocks 0..1023 zero the scatter scratch; block 1024 packs Wo2g^T
// into bf16 MFMA A-fragments (k = s*32 + (l>>4)*8 + j, g = gt*16 + (l&15)).
// ---------------------------------------------------------------------------
__global__ __launch_bounds__(256) void k_init(
    v4f* __restrict__ p, int n16,
    const float* __restrict__ Wo2g, short* __restrict__ wp)
{
    if (blockIdx.x < 1024) {
        v4f z = {0.f, 0.f, 0.f, 0.f};
        for (int i = blockIdx.x * 256 + threadIdx.x; i < n16; i += 1024 * 256)
            p[i] = z;
    } else {
        for (int e = threadIdx.x; e < 8 * 3 * 64 * 8; e += 256) {
            int j  = e & 7;
            int l  = (e >> 3) & 63;
            int ft = e >> 9;                      // s*3 + gt
            int s  = ft / 3, gt = ft - 3 * s;
            int k  = s * 32 + (l >> 4) * 8 + j;
            int g  = gt * 16 + (l & 15);
            wp[e] = f2bf(Wo2g[k * CG + g]);
        }
    }
}

// ---------------------------------------------------------------------------
// Pass 1: per point -> voxel; count + assign compact slots + slot list.
// ---------------------------------------------------------------------------
__global__ __launch_bounds__(256) void k_count(
    const float* __restrict__ pts, float* __restrict__ cnt,
    int* __restrict__ nocc, int* __restrict__ invmap, int* __restrict__ ptvox,
    int* __restrict__ list)
{
    int pn = blockIdx.x * 256 + threadIdx.x;      // < NPTS (exact grid)
    float x = pts[pn * 3 + 0];
    float y = pts[pn * 3 + 1];
    float z = pts[pn * 3 + 2];
    int ix = (int)floorf((x - GMX) / VOXEL);
    int iy = (int)floorf((y - GMY) / VOXEL);
    int iz = (int)floorf((z - GMZ) / VOXEL);
    bool valid = (ix >= 0 && ix < NXc && iy >= 0 && iy < NYc && iz >= 0 && iz < NZc);
    if (!valid) { ptvox[pn] = -1; return; }
    int bt = pn / NPT;
    int btvox = bt * NVOX + iz * (NYc * NXc) + iy * NXc + ix;
    ptvox[pn] = btvox;
    float old = atomicAdd(&cnt[btvox], 1.0f);
    if (old == 0.0f) {
        int s = atomicAdd(nocc, 1);
        invmap[btvox] = s + 1;                    // 0 = empty
        list[s] = btvox;
    }
}

// ---------------------------------------------------------------------------
// megaA: every 9th block = volproj (782), rest = scatterM (6336) —
// interleaved so every CU hosts both roles concurrently.
// P is stored bf16: halves intermediate traffic; each lane's 12x8B stores
// cover a fully contiguous 384B span (write-combinable).
// ---------------------------------------------------------------------------
__global__ __launch_bounds__(256) void k_megaA(
    const float* __restrict__ occ, const short* __restrict__ wp,
    unsigned short* __restrict__ P,
    const float* __restrict__ feats, const int* __restrict__ ptvox,
    const int* __restrict__ invmap, float* __restrict__ compactM)
{
    int bid = blockIdx.x;
    int vpq = bid / 9;
    bool is_vp = (bid % 9 == 0) && (vpq < NB_VP);
    if (is_vp) {
        // ---- volproj ----
        int gwid = (vpq * 256 + threadIdx.x) >> 6;
        if (gwid >= BT * NW64) return;
        int l = threadIdx.x & 63;
        int q = l >> 4, r = l & 15;
        const bfrag8* wf = reinterpret_cast<const bfrag8*>(wp);
        bfrag8 wfr[8][3];
#pragma unroll
        for (int s = 0; s < 8; ++s)
#pragma unroll
            for (int gt = 0; gt < 3; ++gt)
                wfr[s][gt] = wf[(s * 3 + gt) * 64 + l];
        int bt = gwid / NW64;
        int vox0 = (gwid - bt * NW64) * 64;
        int vbase = vox0 + 4 * r;
        int vload = vbase > NVOX - 4 ? NVOX - 4 : vbase;
        const float* b0 = occ + (size_t)bt * CO * NVOX + (size_t)q * 8 * NVOX + vload;
        v4f acc[4][3];
#pragma unroll
        for (int t = 0; t < 4; ++t)
#pragma unroll
            for (int gt = 0; gt < 3; ++gt)
                acc[t][gt] = v4f{0.f, 0.f, 0.f, 0.f};
#pragma unroll
        for (int s = 0; s < 8; ++s) {
            v4f vj[8];
#pragma unroll
            for (int j = 0; j < 8; ++j)
                vj[j] = *reinterpret_cast<const v4f*>(b0 + (size_t)(s * 32 + j) * NVOX);
            bfrag8 bf[4];
#pragma unroll
            for (int t = 0; t < 4; ++t)
#pragma unroll
                for (int j = 0; j < 8; ++j)
                    bf[t][j] = f2bf(vj[j][t]);
#pragma unroll
            for (int t = 0; t < 4; ++t)
#pragma unroll
                for (int gt = 0; gt < 3; ++gt)
                    acc[t][gt] = __builtin_amdgcn_mfma_f32_16x16x32_bf16(
                        wfr[s][gt], bf[t], acc[t][gt], 0, 0, 0);
        }
        unsigned short* o = P + ((size_t)bt * NVOX + vbase) * CG + q * 4;
#pragma unroll
        for (int t = 0; t < 4; ++t) {
            if (vbase + t < NVOX) {
#pragma unroll
                for (int gt = 0; gt < 3; ++gt) {
                    v4s pk;
#pragma unroll
                    for (int e = 0; e < 4; ++e) pk[e] = f2bf(acc[t][gt][e]);
                    *reinterpret_cast<v4s*>(o + t * CG + gt * 16) = pk;
                }
            }
        }
    } else {
        // ---- scatterM ----
        int nvp = (bid + 8) / 9; if (nvp > NB_VP) nvp = NB_VP;
        int scid = bid - nvp;
        int idx = scid * 256 + threadIdx.x;       // (pn)*CG + k
        int k  = idx % CG;
        int pn = idx / CG;
        int bv = ptvox[pn];
        if (bv < 0) return;
        int slot = invmap[bv] - 1;
        atomicAdd(&compactM[(size_t)slot * CG + k], feats[idx]);
    }
}

// ---------------------------------------------------------------------------
// Pass 5: sparse GEMM — compact256[slot][256] = mean[slot][48] @ Wg2o + b.
// ---------------------------------------------------------------------------
__global__ __launch_bounds__(256) void k_gemm(
    const float* __restrict__ compactM, const float* __restrict__ cnt,
    const int* __restrict__ list, const int* __restrict__ noccp,
    const float* __restrict__ Wg2o, const float* __restrict__ bg2o,
    float* __restrict__ compact256)
{
    int nocc = *noccp;
    int s0 = blockIdx.x * 32;
    if (s0 >= nocc) return;                      // uniform per block
    __shared__ float Wl[CG * CO];                // 48 KB, [k][c]
    __shared__ float Ml[32 * CG];                // 6 KB means
    for (int j = threadIdx.x; j < CG * CO; j += 256) Wl[j] = Wg2o[j];
    for (int j = threadIdx.x; j < 32 * CG; j += 256) {
        int v = j / CG, k = j - v * CG;
        int slot = s0 + v;
        float m = 0.f;
        if (slot < nocc) {
            int btvox = list[slot];
            m = compactM[(size_t)slot * CG + k] / cnt[btvox];
        }
        Ml[j] = m;
    }
    __syncthreads();
    int wid = threadIdx.x >> 6, l = threadIdx.x & 63;
    int vb = wid * 8;
    float4 bias = *reinterpret_cast<const float4*>(&bg2o[4 * l]);
    float acc[8][4];
#pragma unroll
    for (int v = 0; v < 8; ++v) {
        acc[v][0] = bias.x; acc[v][1] = bias.y; acc[v][2] = bias.z; acc[v][3] = bias.w;
    }
    for (int k = 0; k < CG; k += 4) {
        float4 w0 = *reinterpret_cast<const float4*>(&Wl[(k + 0) * CO + 4 * l]);
        float4 w1 = *reinterpret_cast<const float4*>(&Wl[(k + 1) * CO + 4 * l]);
        float4 w2 = *reinterpret_cast<const float4*>(&Wl[(k + 2) * CO + 4 * l]);
        float4 w3 = *reinterpret_cast<const float4*>(&Wl[(k + 3) * CO + 4 * l]);
#pragma unroll
        for (int v = 0; v < 8; ++v) {
            float4 m4 = *reinterpret_cast<const float4*>(&Ml[(vb + v) * CG + k]);
            acc[v][0] = fmaf(m4.x, w0.x, acc[v][0]);
            acc[v][1] = fmaf(m4.x, w0.y, acc[v][1]);
            acc[v][2] = fmaf(m4.x, w0.z, acc[v][2]);
            acc[v][3] = fmaf(m4.x, w0.w, acc[v][3]);
            acc[v][0] = fmaf(m4.y, w1.x, acc[v][0]);
            acc[v][1] = fmaf(m4.y, w1.y, acc[v][1]);
            acc[v][2] = fmaf(m4.y, w1.z, acc[v][2]);
            acc[v][3] = fmaf(m4.y, w1.w, acc[v][3]);
            acc[v][0] = fmaf(m4.z, w2.x, acc[v][0]);
            acc[v][1] = fmaf(m4.z, w2.y, acc[v][1]);
            acc[v][2] = fmaf(m4.z, w2.z, acc[v][2]);
            acc[v][3] = fmaf(m4.z, w2.w, acc[v][3]);
            acc[v][0] = fmaf(m4.w, w3.x, acc[v][0]);
            acc[v][1] = fmaf(m4.w, w3.y, acc[v][1]);
            acc[v][2] = fmaf(m4.w, w3.z, acc[v][2]);
            acc[v][3] = fmaf(m4.w, w3.w, acc[v][3]);
        }
    }
#pragma unroll
    for (int v = 0; v < 8; ++v) {
        int slot = s0 + vb + v;
        if (slot < nocc) {
            float4 rr; rr.x = acc[v][0]; rr.y = acc[v][1]; rr.z = acc[v][2]; rr.w = acc[v][3];
            *reinterpret_cast<float4*>(&compact256[(size_t)slot * CO + 4 * l]) = rr;
        }
    }
}

// ---------------------------------------------------------------------------
// megaB: every 5th block = writer (1568), rest = gather (6336) — interleaved.
// Gather reads bf16 P (19 MB — denser lines, mostly L3-resident).
// ---------------------------------------------------------------------------
__global__ __launch_bounds__(256) void k_megaB(
    const int* __restrict__ invmap, const float* __restrict__ compact256,
    float* __restrict__ out0,
    const float* __restrict__ pts, const unsigned short* __restrict__ P,
    const float* __restrict__ bo2g, float* __restrict__ out1)
{
    __shared__ float ldsT[32][260];               // 33.3 KB, padded
    int bid = blockIdx.x;
    int wrq = bid / 5;
    bool is_wr = (bid % 5 == 0) && (wrq < NB_WR);
    if (is_wr) {
        // ---- writer ----
        int bt  = wrq / (NB_WV * 8);
        int rem = wrq - bt * (NB_WV * 8);
        int c0  = (rem / NB_WV) * 32;
        int vb  = (rem - (rem / NB_WV) * NB_WV) * 1024;
        int tid = threadIdx.x;
        int w = tid >> 6, l = tid & 63;
        float* ob = out0 + (size_t)bt * CO * NVOX;
#pragma unroll
        for (int sc = 0; sc < 4; ++sc) {
            int vbase = vb + sc * 256;
            int vox = vbase + tid;
            int slot = (vox < NVOX) ? invmap[bt * NVOX + vox] : 0;
            if (slot > 0) {
                const v4f* row = reinterpret_cast<const v4f*>(
                    compact256 + (size_t)(slot - 1) * CO + c0);
#pragma unroll
                for (int cq = 0; cq < 8; ++cq) {
                    v4f d = row[cq];
#pragma unroll
                    for (int i = 0; i < 4; ++i) ldsT[cq * 4 + i][tid] = d[i];
                }
            } else {
#pragma unroll
                for (int c = 0; c < 32; ++c) ldsT[c][tid] = 0.f;
            }
            __syncthreads();
#pragma unroll
            for (int u = 0; u < 8; ++u) {
                int ci = u * 4 + w;
                int vq = 4 * l;
                int vv = vbase + vq;
                if (vv < NVOX) {
                    v4f val = *reinterpret_cast<const v4f*>(&ldsT[ci][vq]);
                    __builtin_nontemporal_store(val,
                        reinterpret_cast<v4f*>(ob + (size_t)(c0 + ci) * NVOX + vv));
                }
            }
            if (sc < 3) __syncthreads();
        }
    } else {
        // ---- gather ----
        int nwr = (bid + 4) / 5; if (nwr > NB_WR) nwr = NB_WR;
        int gaid = bid - nwr;
        int idx = gaid * 256 + threadIdx.x;       // (pn)*CG + g
        int g  = idx % CG;
        int pn = idx / CG;
        int bt = pn / NPT;
        float x = pts[pn * 3 + 0];
        float y = pts[pn * 3 + 1];
        float z = pts[pn * 3 + 2];
        float gx = (x - GMX) / 80.0f * 2.0f - 1.0f;
        float gy = (y - GMY) / 80.0f * 2.0f - 1.0f;
        float gz = (z - GMZ) / 8.0f  * 2.0f - 1.0f;
        float px = ((gx + 1.0f) * (float)NXc - 1.0f) * 0.5f;
        float py = ((gy + 1.0f) * (float)NYc - 1.0f) * 0.5f;
        float pz = ((gz + 1.0f) * (float)NZc - 1.0f) * 0.5f;
        float fx = floorf(px), fy = floorf(py), fz = floorf(pz);
        float rx = px - fx, ry = py - fy, rz = pz - fz;
        int x0 = (int)fx, y0 = (int)fy, z0 = (int)fz;
        float acc = bo2g[g];
        const unsigned short* Pb = P + (size_t)bt * NVOX * CG;
#pragma unroll
        for (int dz = 0; dz <= 1; ++dz) {
            int zi = z0 + dz;
            if (zi < 0 || zi >= NZc) continue;
            float wz = dz ? rz : 1.0f - rz;
#pragma unroll
            for (int dy = 0; dy <= 1; ++dy) {
                int yi = y0 + dy;
                if (yi < 0 || yi >= NYc) continue;
                float wy = dy ? ry : 1.0f - ry;
#pragma unroll
                for (int dx = 0; dx <= 1; ++dx) {
                    int xi = x0 + dx;
                    if (xi < 0 || xi >= NXc) continue;
                    float wx = dx ? rx : 1.0f - rx;
                    float w = (wx * wy) * wz;
                    int lin = zi * (NYc * NXc) + yi * NXc + xi;
                    acc = fmaf(w, bf2f(Pb[(size_t)lin * CG + g]), acc);
                }
            }
        }
        out1[idx] = acc;
    }
}

// ---------------------------------------------------------------------------
extern "C" void kernel_launch(void* const* d_in, const int* in_sizes, int n_in,
                              void* d_out, int out_size, void* d_ws, size_t ws_size,
                              hipStream_t stream)
{
    const float* centers = (const float*)d_in[0];
    const float* feats   = (const float*)d_in[1];
    const float* occ     = (const float*)d_in[2];
    const float* Wg2o    = (const float*)d_in[3];
    const float* bg2o    = (const float*)d_in[4];
    const float* Wo2g    = (const float*)d_in[5];
    const float* bo2g    = (const float*)d_in[6];

    float* out  = (float*)d_out;
    float* out0 = out;                                   // [BT][CO][NVOX]
    float* out1 = out + (size_t)BT * CO * NVOX;          // [BT][NPT][CG]
    // Packed bf16 W fragments at head of out1 (24 KB): written by k_init,
    // consumed by megaA(volproj), then overwritten by megaB(gather).
    short* wp   = (short*)out1;

    // ws layout: zeroed region first (cnt, nocc, invmap, compactM), then rest.
    char* w = (char*)d_ws;
    float* cnt       = (float*)w;                 w += (size_t)BT * NVOX * 4;       // 800000
    int*   nocc      = (int*)w;                   w += 256;
    int*   invmap    = (int*)w;                   w += (size_t)BT * NVOX * 4;       // 800000
    float* compactM  = (float*)w;                 w += (size_t)MAXS * CG * 4;       // 6488064
    size_t zbytes = (size_t)BT * NVOX * 4 + 256 + (size_t)BT * NVOX * 4
                  + (size_t)MAXS * CG * 4;       // 8,088,320 (16B-divisible)
    int*   ptvox     = (int*)w;                   w += (size_t)NPTS * 4;            // 135168
    int*   list      = (int*)w;                   w += (size_t)MAXS * 4;            // 135168
    float* compact256= (float*)w;                 w += (size_t)MAXS * CO * 4;       // 34603008
    unsigned short* P = (unsigned short*)w;       // BT*NVOX*CG*2 = 19200000

    k_init<<<1025, 256, 0, stream>>>((v4f*)d_ws, (int)(zbytes / 16), Wo2g, wp);
    k_count<<<NPTS / 256, 256, 0, stream>>>(centers, cnt, nocc, invmap, ptvox, list);
    k_megaA<<<NB_VP + NB_SC, 256, 0, stream>>>(occ, wp, P, feats, ptvox, invmap, compactM);
    k_gemm<<<(MAXS + 31) / 32, 256, 0, stream>>>(compactM, cnt, list, nocc, Wg2o, bg2o, compact256);
    k_megaB<<<NB_WR + NB_GA, 256, 0, stream>>>(invmap, compact256, out0, centers, P, bo2g, out1);
}

// Round 15
// 142.263 us; speedup vs baseline: 1.4418x; 1.0187x over previous
//
#include <hip/hip_runtime.h>
#include <hip/hip_bf16.h>

typedef float v4f __attribute__((ext_vector_type(4)));
typedef short v4s __attribute__((ext_vector_type(4)));
typedef short v8s __attribute__((ext_vector_type(8)));
typedef short bfrag8 __attribute__((ext_vector_type(8)));

// Problem constants (match reference)
constexpr int NXc = 100, NYc = 100, NZc = 10;
constexpr int NVOX = NZc * NYc * NXc;      // 100000
constexpr int CO = 256, CG = 48;
constexpr int BT = 2;
constexpr int NPT = 6 * 32 * 88;           // 16896 points per bt
constexpr int NPTS = BT * NPT;             // 33792
constexpr int MAXS = NPTS;                 // max occupied voxels
constexpr int NW64 = (NVOX + 63) / 64;     // 1563 64-vox wave-groups per bt
constexpr int NB_VP = (BT * NW64 + 3) / 4; // 782 volproj blocks
constexpr int NB_SC = NPTS * CG / 256;     // 6336 scatter blocks
constexpr int NB_WV = (NVOX + 1023) / 1024;// 98 vox-groups for writer
constexpr int NB_WR = NB_WV * 8 * BT;      // 1568 writer blocks
constexpr int NB_GA = NPTS * CG / 256;     // 6336 gather blocks
constexpr float GMX = -40.0f, GMY = -40.0f, GMZ = -2.0f;
constexpr float VOXEL = 0.8f;

static __device__ __forceinline__ short f2bf(float f) {
    __hip_bfloat16 h = __float2bfloat16(f);
    return __builtin_bit_cast(short, h);
}
static __device__ __forceinline__ float bf2f(unsigned short u) {
    unsigned v = (unsigned)u << 16;
    return __builtin_bit_cast(float, v);
}

// ---------------------------------------------------------------------------
// Pass 0: blocks 0..1023 zero the scatter scratch; block 1024 packs Wo2g^T
// into bf16 MFMA A-fragments (k = s*32 + (l>>4)*8 + j, g = gt*16 + (l&15)).
// ---------------------------------------------------------------------------
__global__ __launch_bounds__(256) void k_init(
    v4f* __restrict__ p, int n16,
    const float* __restrict__ Wo2g, short* __restrict__ wp)
{
    if (blockIdx.x < 1024) {
        v4f z = {0.f, 0.f, 0.f, 0.f};
        for (int i = blockIdx.x * 256 + threadIdx.x; i < n16; i += 1024 * 256)
            p[i] = z;
    } else {
        for (int e = threadIdx.x; e < 8 * 3 * 64 * 8; e += 256) {
            int j  = e & 7;
            int l  = (e >> 3) & 63;
            int ft = e >> 9;                      // s*3 + gt
            int s  = ft / 3, gt = ft - 3 * s;
            int k  = s * 32 + (l >> 4) * 8 + j;
            int g  = gt * 16 + (l & 15);
            wp[e] = f2bf(Wo2g[k * CG + g]);
        }
    }
}

// ---------------------------------------------------------------------------
// Pass 1: per point -> voxel; count + assign compact slots + slot list.
// ---------------------------------------------------------------------------
__global__ __launch_bounds__(256) void k_count(
    const float* __restrict__ pts, float* __restrict__ cnt,
    int* __restrict__ nocc, int* __restrict__ invmap, int* __restrict__ ptvox,
    int* __restrict__ list)
{
    int pn = blockIdx.x * 256 + threadIdx.x;      // < NPTS (exact grid)
    float x = pts[pn * 3 + 0];
    float y = pts[pn * 3 + 1];
    float z = pts[pn * 3 + 2];
    int ix = (int)floorf((x - GMX) / VOXEL);
    int iy = (int)floorf((y - GMY) / VOXEL);
    int iz = (int)floorf((z - GMZ) / VOXEL);
    bool valid = (ix >= 0 && ix < NXc && iy >= 0 && iy < NYc && iz >= 0 && iz < NZc);
    if (!valid) { ptvox[pn] = -1; return; }
    int bt = pn / NPT;
    int btvox = bt * NVOX + iz * (NYc * NXc) + iy * NXc + ix;
    ptvox[pn] = btvox;
    float old = atomicAdd(&cnt[btvox], 1.0f);
    if (old == 0.0f) {
        int s = atomicAdd(nocc, 1);
        invmap[btvox] = s + 1;                    // 0 = empty
        list[s] = btvox;
    }
}

// ---------------------------------------------------------------------------
// megaA: every 9th block = volproj (782), rest = scatterM (6336) —
// interleaved. W fragments are NOT register-hoisted (re-read per K-step;
// 24 KB shared, L1-hot) and launch_bounds(256,4) caps VGPR at 128 ->
// 4 waves/SIMD -> 2x in-flight occ bytes (latency-hiding arithmetic).
// ---------------------------------------------------------------------------
__global__ __launch_bounds__(256, 4) void k_megaA(
    const float* __restrict__ occ, const short* __restrict__ wp,
    unsigned short* __restrict__ P,
    const float* __restrict__ feats, const int* __restrict__ ptvox,
    const int* __restrict__ invmap, float* __restrict__ compactM)
{
    int bid = blockIdx.x;
    int vpq = bid / 9;
    bool is_vp = (bid % 9 == 0) && (vpq < NB_VP);
    if (is_vp) {
        // ---- volproj ----
        int gwid = (vpq * 256 + threadIdx.x) >> 6;
        if (gwid >= BT * NW64) return;
        int l = threadIdx.x & 63;
        int q = l >> 4, r = l & 15;
        const bfrag8* wf = reinterpret_cast<const bfrag8*>(wp);
        int bt = gwid / NW64;
        int vox0 = (gwid - bt * NW64) * 64;
        int vbase = vox0 + 4 * r;
        int vload = vbase > NVOX - 4 ? NVOX - 4 : vbase;
        const float* b0 = occ + (size_t)bt * CO * NVOX + (size_t)q * 8 * NVOX + vload;
        v4f acc[4][3];
#pragma unroll
        for (int t = 0; t < 4; ++t)
#pragma unroll
            for (int gt = 0; gt < 3; ++gt)
                acc[t][gt] = v4f{0.f, 0.f, 0.f, 0.f};
#pragma unroll
        for (int s = 0; s < 8; ++s) {
            v4f vj[8];
#pragma unroll
            for (int j = 0; j < 8; ++j)
                vj[j] = *reinterpret_cast<const v4f*>(b0 + (size_t)(s * 32 + j) * NVOX);
            bfrag8 bf[4];
#pragma unroll
            for (int t = 0; t < 4; ++t)
#pragma unroll
                for (int j = 0; j < 8; ++j)
                    bf[t][j] = f2bf(vj[j][t]);
#pragma unroll
            for (int gt = 0; gt < 3; ++gt) {
                bfrag8 a = wf[(s * 3 + gt) * 64 + l];
#pragma unroll
                for (int t = 0; t < 4; ++t)
                    acc[t][gt] = __builtin_amdgcn_mfma_f32_16x16x32_bf16(
                        a, bf[t], acc[t][gt], 0, 0, 0);
            }
        }
        unsigned short* o = P + ((size_t)bt * NVOX + vbase) * CG + q * 4;
#pragma unroll
        for (int t = 0; t < 4; ++t) {
            if (vbase + t < NVOX) {
#pragma unroll
                for (int gt = 0; gt < 3; ++gt) {
                    v4s pk;
#pragma unroll
                    for (int e = 0; e < 4; ++e) pk[e] = f2bf(acc[t][gt][e]);
                    *reinterpret_cast<v4s*>(o + t * CG + gt * 16) = pk;
                }
            }
        }
    } else {
        // ---- scatterM ----
        int nvp = (bid + 8) / 9; if (nvp > NB_VP) nvp = NB_VP;
        int scid = bid - nvp;
        int idx = scid * 256 + threadIdx.x;       // (pn)*CG + k
        int k  = idx % CG;
        int pn = idx / CG;
        int bv = ptvox[pn];
        if (bv < 0) return;
        int slot = invmap[bv] - 1;
        atomicAdd(&compactM[(size_t)slot * CG + k], feats[idx]);
    }
}

// ---------------------------------------------------------------------------
// Pass 5: sparse GEMM — compact256h[slot][256] (bf16) = mean[48] @ Wg2o + b.
// ---------------------------------------------------------------------------
__global__ __launch_bounds__(256) void k_gemm(
    const float* __restrict__ compactM, const float* __restrict__ cnt,
    const int* __restrict__ list, const int* __restrict__ noccp,
    const float* __restrict__ Wg2o, const float* __restrict__ bg2o,
    unsigned short* __restrict__ compact256h)
{
    int nocc = *noccp;
    int s0 = blockIdx.x * 32;
    if (s0 >= nocc) return;                      // uniform per block
    __shared__ float Wl[CG * CO];                // 48 KB, [k][c]
    __shared__ float Ml[32 * CG];                // 6 KB means
    for (int j = threadIdx.x; j < CG * CO; j += 256) Wl[j] = Wg2o[j];
    for (int j = threadIdx.x; j < 32 * CG; j += 256) {
        int v = j / CG, k = j - v * CG;
        int slot = s0 + v;
        float m = 0.f;
        if (slot < nocc) {
            int btvox = list[slot];
            m = compactM[(size_t)slot * CG + k] / cnt[btvox];
        }
        Ml[j] = m;
    }
    __syncthreads();
    int wid = threadIdx.x >> 6, l = threadIdx.x & 63;
    int vb = wid * 8;
    float4 bias = *reinterpret_cast<const float4*>(&bg2o[4 * l]);
    float acc[8][4];
#pragma unroll
    for (int v = 0; v < 8; ++v) {
        acc[v][0] = bias.x; acc[v][1] = bias.y; acc[v][2] = bias.z; acc[v][3] = bias.w;
    }
    for (int k = 0; k < CG; k += 4) {
        float4 w0 = *reinterpret_cast<const float4*>(&Wl[(k + 0) * CO + 4 * l]);
        float4 w1 = *reinterpret_cast<const float4*>(&Wl[(k + 1) * CO + 4 * l]);
        float4 w2 = *reinterpret_cast<const float4*>(&Wl[(k + 2) * CO + 4 * l]);
        float4 w3 = *reinterpret_cast<const float4*>(&Wl[(k + 3) * CO + 4 * l]);
#pragma unroll
        for (int v = 0; v < 8; ++v) {
            float4 m4 = *reinterpret_cast<const float4*>(&Ml[(vb + v) * CG + k]);
            acc[v][0] = fmaf(m4.x, w0.x, acc[v][0]);
            acc[v][1] = fmaf(m4.x, w0.y, acc[v][1]);
            acc[v][2] = fmaf(m4.x, w0.z, acc[v][2]);
            acc[v][3] = fmaf(m4.x, w0.w, acc[v][3]);
            acc[v][0] = fmaf(m4.y, w1.x, acc[v][0]);
            acc[v][1] = fmaf(m4.y, w1.y, acc[v][1]);
            acc[v][2] = fmaf(m4.y, w1.z, acc[v][2]);
            acc[v][3] = fmaf(m4.y, w1.w, acc[v][3]);
            acc[v][0] = fmaf(m4.z, w2.x, acc[v][0]);
            acc[v][1] = fmaf(m4.z, w2.y, acc[v][1]);
            acc[v][2] = fmaf(m4.z, w2.z, acc[v][2]);
            acc[v][3] = fmaf(m4.z, w2.w, acc[v][3]);
            acc[v][0] = fmaf(m4.w, w3.x, acc[v][0]);
            acc[v][1] = fmaf(m4.w, w3.y, acc[v][1]);
            acc[v][2] = fmaf(m4.w, w3.z, acc[v][2]);
            acc[v][3] = fmaf(m4.w, w3.w, acc[v][3]);
        }
    }
#pragma unroll
    for (int v = 0; v < 8; ++v) {
        int slot = s0 + vb + v;
        if (slot < nocc) {
            v4s rr;
#pragma unroll
            for (int e = 0; e < 4; ++e) rr[e] = f2bf(acc[v][e]);
            *reinterpret_cast<v4s*>(&compact256h[(size_t)slot * CO + 4 * l]) = rr;
        }
    }
}

// ---------------------------------------------------------------------------
// megaB: every 5th block = writer (1568), rest = gather (6336) — interleaved.
// Writer reads bf16 compact rows as contiguous v8s vectors (no scalar
// gathers); gather reads bf16 P (19 MB, denser lines).
// ---------------------------------------------------------------------------
__global__ __launch_bounds__(256) void k_megaB(
    const int* __restrict__ invmap, const unsigned short* __restrict__ compact256h,
    float* __restrict__ out0,
    const float* __restrict__ pts, const unsigned short* __restrict__ P,
    const float* __restrict__ bo2g, float* __restrict__ out1)
{
    __shared__ float ldsT[32][260];               // 33.3 KB, padded
    int bid = blockIdx.x;
    int wrq = bid / 5;
    bool is_wr = (bid % 5 == 0) && (wrq < NB_WR);
    if (is_wr) {
        // ---- writer ----
        int bt  = wrq / (NB_WV * 8);
        int rem = wrq - bt * (NB_WV * 8);
        int c0  = (rem / NB_WV) * 32;
        int vb  = (rem - (rem / NB_WV) * NB_WV) * 1024;
        int tid = threadIdx.x;
        int w = tid >> 6, l = tid & 63;
        float* ob = out0 + (size_t)bt * CO * NVOX;
#pragma unroll
        for (int sc = 0; sc < 4; ++sc) {
            int vbase = vb + sc * 256;
            int vox = vbase + tid;
            int slot = (vox < NVOX) ? invmap[bt * NVOX + vox] : 0;
            if (slot > 0) {
                const v8s* row = reinterpret_cast<const v8s*>(
                    compact256h + (size_t)(slot - 1) * CO + c0);
#pragma unroll
                for (int cq = 0; cq < 4; ++cq) {
                    v8s d = row[cq];
#pragma unroll
                    for (int i = 0; i < 8; ++i)
                        ldsT[cq * 8 + i][tid] = bf2f((unsigned short)d[i]);
                }
            } else {
#pragma unroll
                for (int c = 0; c < 32; ++c) ldsT[c][tid] = 0.f;
            }
            __syncthreads();
#pragma unroll
            for (int u = 0; u < 8; ++u) {
                int ci = u * 4 + w;
                int vq = 4 * l;
                int vv = vbase + vq;
                if (vv < NVOX) {
                    v4f val = *reinterpret_cast<const v4f*>(&ldsT[ci][vq]);
                    __builtin_nontemporal_store(val,
                        reinterpret_cast<v4f*>(ob + (size_t)(c0 + ci) * NVOX + vv));
                }
            }
            if (sc < 3) __syncthreads();
        }
    } else {
        // ---- gather ----
        int nwr = (bid + 4) / 5; if (nwr > NB_WR) nwr = NB_WR;
        int gaid = bid - nwr;
        int idx = gaid * 256 + threadIdx.x;       // (pn)*CG + g
        int g  = idx % CG;
        int pn = idx / CG;
        int bt = pn / NPT;
        float x = pts[pn * 3 + 0];
        float y = pts[pn * 3 + 1];
        float z = pts[pn * 3 + 2];
        float gx = (x - GMX) / 80.0f * 2.0f - 1.0f;
        float gy = (y - GMY) / 80.0f * 2.0f - 1.0f;
        float gz = (z - GMZ) / 8.0f  * 2.0f - 1.0f;
        float px = ((gx + 1.0f) * (float)NXc - 1.0f) * 0.5f;
        float py = ((gy + 1.0f) * (float)NYc - 1.0f) * 0.5f;
        float pz = ((gz + 1.0f) * (float)NZc - 1.0f) * 0.5f;
        float fx = floorf(px), fy = floorf(py), fz = floorf(pz);
        float rx = px - fx, ry = py - fy, rz = pz - fz;
        int x0 = (int)fx, y0 = (int)fy, z0 = (int)fz;
        float acc = bo2g[g];
        const unsigned short* Pb = P + (size_t)bt * NVOX * CG;
#pragma unroll
        for (int dz = 0; dz <= 1; ++dz) {
            int zi = z0 + dz;
            if (zi < 0 || zi >= NZc) continue;
            float wz = dz ? rz : 1.0f - rz;
#pragma unroll
            for (int dy = 0; dy <= 1; ++dy) {
                int yi = y0 + dy;
                if (yi < 0 || yi >= NYc) continue;
                float wy = dy ? ry : 1.0f - ry;
#pragma unroll
                for (int dx = 0; dx <= 1; ++dx) {
                    int xi = x0 + dx;
                    if (xi < 0 || xi >= NXc) continue;
                    float wx = dx ? rx : 1.0f - rx;
                    float w = (wx * wy) * wz;
                    int lin = zi * (NYc * NXc) + yi * NXc + xi;
                    acc = fmaf(w, bf2f(Pb[(size_t)lin * CG + g]), acc);
                }
            }
        }
        out1[idx] = acc;
    }
}

// ---------------------------------------------------------------------------
extern "C" void kernel_launch(void* const* d_in, const int* in_sizes, int n_in,
                              void* d_out, int out_size, void* d_ws, size_t ws_size,
                              hipStream_t stream)
{
    const float* centers = (const float*)d_in[0];
    const float* feats   = (const float*)d_in[1];
    const float* occ     = (const float*)d_in[2];
    const float* Wg2o    = (const float*)d_in[3];
    const float* bg2o    = (const float*)d_in[4];
    const float* Wo2g    = (const float*)d_in[5];
    const float* bo2g    = (const float*)d_in[6];

    float* out  = (float*)d_out;
    float* out0 = out;                                   // [BT][CO][NVOX]
    float* out1 = out + (size_t)BT * CO * NVOX;          // [BT][NPT][CG]
    // Packed bf16 W fragments at head of out1 (24 KB): written by k_init,
    // consumed by megaA(volproj), then overwritten by megaB(gather).
    short* wp   = (short*)out1;

    // ws layout: zeroed region first (cnt, nocc, invmap, compactM), then rest.
    char* w = (char*)d_ws;
    float* cnt       = (float*)w;                 w += (size_t)BT * NVOX * 4;       // 800000
    int*   nocc      = (int*)w;                   w += 256;
    int*   invmap    = (int*)w;                   w += (size_t)BT * NVOX * 4;       // 800000
    float* compactM  = (float*)w;                 w += (size_t)MAXS * CG * 4;       // 6488064
    size_t zbytes = (size_t)BT * NVOX * 4 + 256 + (size_t)BT * NVOX * 4
                  + (size_t)MAXS * CG * 4;       // 8,088,320 (16B-divisible)
    int*   ptvox     = (int*)w;                   w += (size_t)NPTS * 4;            // 135168
    int*   list      = (int*)w;                   w += (size_t)MAXS * 4;            // 135168
    unsigned short* compact256h = (unsigned short*)w;  w += (size_t)MAXS * CO * 2;  // 17301504
    unsigned short* P = (unsigned short*)w;       // BT*NVOX*CG*2 = 19200000

    k_init<<<1025, 256, 0, stream>>>((v4f*)d_ws, (int)(zbytes / 16), Wo2g, wp);
    k_count<<<NPTS / 256, 256, 0, stream>>>(centers, cnt, nocc, invmap, ptvox, list);
    k_megaA<<<NB_VP + NB_SC, 256, 0, stream>>>(occ, wp, P, feats, ptvox, invmap, compactM);
    k_gemm<<<(MAXS + 31) / 32, 256, 0, stream>>>(compactM, cnt, list, nocc, Wg2o, bg2o, compact256h);
    k_megaB<<<NB_WR + NB_GA, 256, 0, stream>>>(invmap, compact256h, out0, centers, P, bo2g, out1);
}

// Round 16
// 136.189 us; speedup vs baseline: 1.5061x; 1.0446x over previous
//
#include <hip/hip_runtime.h>
#include <hip/hip_bf16.h>

typedef float v4f __attribute__((ext_vector_type(4)));
typedef short v4s __attribute__((ext_vector_type(4)));
typedef short v8s __attribute__((ext_vector_type(8)));
typedef short bfrag8 __attribute__((ext_vector_type(8)));

// Problem constants (match reference)
constexpr int NXc = 100, NYc = 100, NZc = 10;
constexpr int NVOX = NZc * NYc * NXc;      // 100000
constexpr int CO = 256, CG = 48;
constexpr int BT = 2;
constexpr int NPT = 6 * 32 * 88;           // 16896 points per bt
constexpr int NPTS = BT * NPT;             // 33792
constexpr int MAXS = NPTS;                 // max occupied voxels
constexpr int NW64 = (NVOX + 63) / 64;     // 1563 64-vox wave-groups per bt
constexpr int NB_VP = (BT * NW64 + 3) / 4; // 782 volproj blocks
constexpr int NB_SC = NPTS * CG / 256;     // 6336 scatter blocks
constexpr int NB_WV = (NVOX + 1023) / 1024;// 98 vox-groups for writer
constexpr int NB_WR = NB_WV * 8 * BT;      // 1568 writer blocks
constexpr int NB_GA = NPTS * CG / 256;     // 6336 gather blocks
constexpr int NB_CT = NPTS / 256;          // 132 count blocks
constexpr float GMX = -40.0f, GMY = -40.0f, GMZ = -2.0f;
constexpr float VOXEL = 0.8f;

static __device__ __forceinline__ short f2bf(float f) {
    __hip_bfloat16 h = __float2bfloat16(f);
    return __builtin_bit_cast(short, h);
}
static __device__ __forceinline__ float bf2f(unsigned short u) {
    unsigned v = (unsigned)u << 16;
    return __builtin_bit_cast(float, v);
}

// ---------------------------------------------------------------------------
// Pass 0: blocks 0..199 zero cnt/nocc/invmap (1.6 MB); block 200 packs
// Wo2g^T into bf16 MFMA A-fragments (k = s*32+(l>>4)*8+j, g = gt*16+(l&15)).
// compactM zeroing moved into the k_count launch (extra blocks).
// ---------------------------------------------------------------------------
__global__ __launch_bounds__(256) void k_init(
    v4f* __restrict__ p, int n16,
    const float* __restrict__ Wo2g, short* __restrict__ wp)
{
    if (blockIdx.x < 200) {
        v4f z = {0.f, 0.f, 0.f, 0.f};
        for (int i = blockIdx.x * 256 + threadIdx.x; i < n16; i += 200 * 256)
            p[i] = z;
    } else {
        for (int e = threadIdx.x; e < 8 * 3 * 64 * 8; e += 256) {
            int j  = e & 7;
            int l  = (e >> 3) & 63;
            int ft = e >> 9;                      // s*3 + gt
            int s  = ft / 3, gt = ft - 3 * s;
            int k  = s * 32 + (l >> 4) * 8 + j;
            int g  = gt * 16 + (l & 15);
            wp[e] = f2bf(Wo2g[k * CG + g]);
        }
    }
}

// ---------------------------------------------------------------------------
// Pass 1: blocks [0,NB_CT): per point -> voxel; count + compact slots + list.
// Blocks >= NB_CT: zero compactM (needed only by megaA's scatterM, which runs
// in the NEXT launch -> kernel boundary guarantees ordering).
// ---------------------------------------------------------------------------
__global__ __launch_bounds__(256) void k_count(
    const float* __restrict__ pts, float* __restrict__ cnt,
    int* __restrict__ nocc, int* __restrict__ invmap, int* __restrict__ ptvox,
    int* __restrict__ list, v4f* __restrict__ cmz, int cmz16)
{
    if (blockIdx.x >= NB_CT) {
        int i = (blockIdx.x - NB_CT) * 256 + threadIdx.x;
        if (i < cmz16) cmz[i] = v4f{0.f, 0.f, 0.f, 0.f};
        return;
    }
    int pn = blockIdx.x * 256 + threadIdx.x;      // < NPTS (exact grid)
    float x = pts[pn * 3 + 0];
    float y = pts[pn * 3 + 1];
    float z = pts[pn * 3 + 2];
    int ix = (int)floorf((x - GMX) / VOXEL);
    int iy = (int)floorf((y - GMY) / VOXEL);
    int iz = (int)floorf((z - GMZ) / VOXEL);
    bool valid = (ix >= 0 && ix < NXc && iy >= 0 && iy < NYc && iz >= 0 && iz < NZc);
    if (!valid) { ptvox[pn] = -1; return; }
    int bt = pn / NPT;
    int btvox = bt * NVOX + iz * (NYc * NXc) + iy * NXc + ix;
    ptvox[pn] = btvox;
    float old = atomicAdd(&cnt[btvox], 1.0f);
    if (old == 0.0f) {
        int s = atomicAdd(nocc, 1);
        invmap[btvox] = s + 1;                    // 0 = empty
        list[s] = btvox;
    }
}

// ---------------------------------------------------------------------------
// megaA: every 9th block = volproj (782), rest = scatterM (6336) —
// interleaved so every CU hosts both roles concurrently.
// ---------------------------------------------------------------------------
__global__ __launch_bounds__(256, 4) void k_megaA(
    const float* __restrict__ occ, const short* __restrict__ wp,
    unsigned short* __restrict__ P,
    const float* __restrict__ feats, const int* __restrict__ ptvox,
    const int* __restrict__ invmap, float* __restrict__ compactM)
{
    int bid = blockIdx.x;
    int vpq = bid / 9;
    bool is_vp = (bid % 9 == 0) && (vpq < NB_VP);
    if (is_vp) {
        // ---- volproj ----
        int gwid = (vpq * 256 + threadIdx.x) >> 6;
        if (gwid >= BT * NW64) return;
        int l = threadIdx.x & 63;
        int q = l >> 4, r = l & 15;
        const bfrag8* wf = reinterpret_cast<const bfrag8*>(wp);
        int bt = gwid / NW64;
        int vox0 = (gwid - bt * NW64) * 64;
        int vbase = vox0 + 4 * r;
        int vload = vbase > NVOX - 4 ? NVOX - 4 : vbase;
        const float* b0 = occ + (size_t)bt * CO * NVOX + (size_t)q * 8 * NVOX + vload;
        v4f acc[4][3];
#pragma unroll
        for (int t = 0; t < 4; ++t)
#pragma unroll
            for (int gt = 0; gt < 3; ++gt)
                acc[t][gt] = v4f{0.f, 0.f, 0.f, 0.f};
#pragma unroll
        for (int s = 0; s < 8; ++s) {
            v4f vj[8];
#pragma unroll
            for (int j = 0; j < 8; ++j)
                vj[j] = *reinterpret_cast<const v4f*>(b0 + (size_t)(s * 32 + j) * NVOX);
            bfrag8 bf[4];
#pragma unroll
            for (int t = 0; t < 4; ++t)
#pragma unroll
                for (int j = 0; j < 8; ++j)
                    bf[t][j] = f2bf(vj[j][t]);
#pragma unroll
            for (int gt = 0; gt < 3; ++gt) {
                bfrag8 a = wf[(s * 3 + gt) * 64 + l];
#pragma unroll
                for (int t = 0; t < 4; ++t)
                    acc[t][gt] = __builtin_amdgcn_mfma_f32_16x16x32_bf16(
                        a, bf[t], acc[t][gt], 0, 0, 0);
            }
        }
        unsigned short* o = P + ((size_t)bt * NVOX + vbase) * CG + q * 4;
#pragma unroll
        for (int t = 0; t < 4; ++t) {
            if (vbase + t < NVOX) {
#pragma unroll
                for (int gt = 0; gt < 3; ++gt) {
                    v4s pk;
#pragma unroll
                    for (int e = 0; e < 4; ++e) pk[e] = f2bf(acc[t][gt][e]);
                    *reinterpret_cast<v4s*>(o + t * CG + gt * 16) = pk;
                }
            }
        }
    } else {
        // ---- scatterM ----
        int nvp = (bid + 8) / 9; if (nvp > NB_VP) nvp = NB_VP;
        int scid = bid - nvp;
        int idx = scid * 256 + threadIdx.x;       // (pn)*CG + k
        int k  = idx % CG;
        int pn = idx / CG;
        int bv = ptvox[pn];
        if (bv < 0) return;
        int slot = invmap[bv] - 1;
        atomicAdd(&compactM[(size_t)slot * CG + k], feats[idx]);
    }
}

// ---------------------------------------------------------------------------
// Pass 5: sparse GEMM — compact256h[slot][256] (bf16) = mean[48] @ Wg2o + b.
// ---------------------------------------------------------------------------
__global__ __launch_bounds__(256) void k_gemm(
    const float* __restrict__ compactM, const float* __restrict__ cnt,
    const int* __restrict__ list, const int* __restrict__ noccp,
    const float* __restrict__ Wg2o, const float* __restrict__ bg2o,
    unsigned short* __restrict__ compact256h)
{
    int nocc = *noccp;
    int s0 = blockIdx.x * 32;
    if (s0 >= nocc) return;                      // uniform per block
    __shared__ float Wl[CG * CO];                // 48 KB, [k][c]
    __shared__ float Ml[32 * CG];                // 6 KB means
    for (int j = threadIdx.x; j < CG * CO; j += 256) Wl[j] = Wg2o[j];
    for (int j = threadIdx.x; j < 32 * CG; j += 256) {
        int v = j / CG, k = j - v * CG;
        int slot = s0 + v;
        float m = 0.f;
        if (slot < nocc) {
            int btvox = list[slot];
            m = compactM[(size_t)slot * CG + k] / cnt[btvox];
        }
        Ml[j] = m;
    }
    __syncthreads();
    int wid = threadIdx.x >> 6, l = threadIdx.x & 63;
    int vb = wid * 8;
    float4 bias = *reinterpret_cast<const float4*>(&bg2o[4 * l]);
    float acc[8][4];
#pragma unroll
    for (int v = 0; v < 8; ++v) {
        acc[v][0] = bias.x; acc[v][1] = bias.y; acc[v][2] = bias.z; acc[v][3] = bias.w;
    }
    for (int k = 0; k < CG; k += 4) {
        float4 w0 = *reinterpret_cast<const float4*>(&Wl[(k + 0) * CO + 4 * l]);
        float4 w1 = *reinterpret_cast<const float4*>(&Wl[(k + 1) * CO + 4 * l]);
        float4 w2 = *reinterpret_cast<const float4*>(&Wl[(k + 2) * CO + 4 * l]);
        float4 w3 = *reinterpret_cast<const float4*>(&Wl[(k + 3) * CO + 4 * l]);
#pragma unroll
        for (int v = 0; v < 8; ++v) {
            float4 m4 = *reinterpret_cast<const float4*>(&Ml[(vb + v) * CG + k]);
            acc[v][0] = fmaf(m4.x, w0.x, acc[v][0]);
            acc[v][1] = fmaf(m4.x, w0.y, acc[v][1]);
            acc[v][2] = fmaf(m4.x, w0.z, acc[v][2]);
            acc[v][3] = fmaf(m4.x, w0.w, acc[v][3]);
            acc[v][0] = fmaf(m4.y, w1.x, acc[v][0]);
            acc[v][1] = fmaf(m4.y, w1.y, acc[v][1]);
            acc[v][2] = fmaf(m4.y, w1.z, acc[v][2]);
            acc[v][3] = fmaf(m4.y, w1.w, acc[v][3]);
            acc[v][0] = fmaf(m4.z, w2.x, acc[v][0]);
            acc[v][1] = fmaf(m4.z, w2.y, acc[v][1]);
            acc[v][2] = fmaf(m4.z, w2.z, acc[v][2]);
            acc[v][3] = fmaf(m4.z, w2.w, acc[v][3]);
            acc[v][0] = fmaf(m4.w, w3.x, acc[v][0]);
            acc[v][1] = fmaf(m4.w, w3.y, acc[v][1]);
            acc[v][2] = fmaf(m4.w, w3.z, acc[v][2]);
            acc[v][3] = fmaf(m4.w, w3.w, acc[v][3]);
        }
    }
#pragma unroll
    for (int v = 0; v < 8; ++v) {
        int slot = s0 + vb + v;
        if (slot < nocc) {
            v4s rr;
#pragma unroll
            for (int e = 0; e < 4; ++e) rr[e] = f2bf(acc[v][e]);
            *reinterpret_cast<v4s*>(&compact256h[(size_t)slot * CO + 4 * l]) = rr;
        }
    }
}

// ---------------------------------------------------------------------------
// megaB: every 5th block = writer (1568), rest = gather (6336) — interleaved.
// ---------------------------------------------------------------------------
__global__ __launch_bounds__(256) void k_megaB(
    const int* __restrict__ invmap, const unsigned short* __restrict__ compact256h,
    float* __restrict__ out0,
    const float* __restrict__ pts, const unsigned short* __restrict__ P,
    const float* __restrict__ bo2g, float* __restrict__ out1)
{
    __shared__ float ldsT[32][260];               // 33.3 KB, padded
    int bid = blockIdx.x;
    int wrq = bid / 5;
    bool is_wr = (bid % 5 == 0) && (wrq < NB_WR);
    if (is_wr) {
        // ---- writer ----
        int bt  = wrq / (NB_WV * 8);
        int rem = wrq - bt * (NB_WV * 8);
        int c0  = (rem / NB_WV) * 32;
        int vb  = (rem - (rem / NB_WV) * NB_WV) * 1024;
        int tid = threadIdx.x;
        int w = tid >> 6, l = tid & 63;
        float* ob = out0 + (size_t)bt * CO * NVOX;
#pragma unroll
        for (int sc = 0; sc < 4; ++sc) {
            int vbase = vb + sc * 256;
            int vox = vbase + tid;
            int slot = (vox < NVOX) ? invmap[bt * NVOX + vox] : 0;
            if (slot > 0) {
                const v8s* row = reinterpret_cast<const v8s*>(
                    compact256h + (size_t)(slot - 1) * CO + c0);
#pragma unroll
                for (int cq = 0; cq < 4; ++cq) {
                    v8s d = row[cq];
#pragma unroll
                    for (int i = 0; i < 8; ++i)
                        ldsT[cq * 8 + i][tid] = bf2f((unsigned short)d[i]);
                }
            } else {
#pragma unroll
                for (int c = 0; c < 32; ++c) ldsT[c][tid] = 0.f;
            }
            __syncthreads();
#pragma unroll
            for (int u = 0; u < 8; ++u) {
                int ci = u * 4 + w;
                int vq = 4 * l;
                int vv = vbase + vq;
                if (vv < NVOX) {
                    v4f val = *reinterpret_cast<const v4f*>(&ldsT[ci][vq]);
                    __builtin_nontemporal_store(val,
                        reinterpret_cast<v4f*>(ob + (size_t)(c0 + ci) * NVOX + vv));
                }
            }
            if (sc < 3) __syncthreads();
        }
    } else {
        // ---- gather ----
        int nwr = (bid + 4) / 5; if (nwr > NB_WR) nwr = NB_WR;
        int gaid = bid - nwr;
        int idx = gaid * 256 + threadIdx.x;       // (pn)*CG + g
        int g  = idx % CG;
        int pn = idx / CG;
        int bt = pn / NPT;
        float x = pts[pn * 3 + 0];
        float y = pts[pn * 3 + 1];
        float z = pts[pn * 3 + 2];
        float gx = (x - GMX) / 80.0f * 2.0f - 1.0f;
        float gy = (y - GMY) / 80.0f * 2.0f - 1.0f;
        float gz = (z - GMZ) / 8.0f  * 2.0f - 1.0f;
        float px = ((gx + 1.0f) * (float)NXc - 1.0f) * 0.5f;
        float py = ((gy + 1.0f) * (float)NYc - 1.0f) * 0.5f;
        float pz = ((gz + 1.0f) * (float)NZc - 1.0f) * 0.5f;
        float fx = floorf(px), fy = floorf(py), fz = floorf(pz);
        float rx = px - fx, ry = py - fy, rz = pz - fz;
        int x0 = (int)fx, y0 = (int)fy, z0 = (int)fz;
        float acc = bo2g[g];
        const unsigned short* Pb = P + (size_t)bt * NVOX * CG;
#pragma unroll
        for (int dz = 0; dz <= 1; ++dz) {
            int zi = z0 + dz;
            if (zi < 0 || zi >= NZc) continue;
            float wz = dz ? rz : 1.0f - rz;
#pragma unroll
            for (int dy = 0; dy <= 1; ++dy) {
                int yi = y0 + dy;
                if (yi < 0 || yi >= NYc) continue;
                float wy = dy ? ry : 1.0f - ry;
#pragma unroll
                for (int dx = 0; dx <= 1; ++dx) {
                    int xi = x0 + dx;
                    if (xi < 0 || xi >= NXc) continue;
                    float wx = dx ? rx : 1.0f - rx;
                    float w = (wx * wy) * wz;
                    int lin = zi * (NYc * NXc) + yi * NXc + xi;
                    acc = fmaf(w, bf2f(Pb[(size_t)lin * CG + g]), acc);
                }
            }
        }
        out1[idx] = acc;
    }
}

// ---------------------------------------------------------------------------
extern "C" void kernel_launch(void* const* d_in, const int* in_sizes, int n_in,
                              void* d_out, int out_size, void* d_ws, size_t ws_size,
                              hipStream_t stream)
{
    const float* centers = (const float*)d_in[0];
    const float* feats   = (const float*)d_in[1];
    const float* occ     = (const float*)d_in[2];
    const float* Wg2o    = (const float*)d_in[3];
    const float* bg2o    = (const float*)d_in[4];
    const float* Wo2g    = (const float*)d_in[5];
    const float* bo2g    = (const float*)d_in[6];

    float* out  = (float*)d_out;
    float* out0 = out;                                   // [BT][CO][NVOX]
    float* out1 = out + (size_t)BT * CO * NVOX;          // [BT][NPT][CG]
    // Packed bf16 W fragments at head of out1 (24 KB): written by k_init,
    // consumed by megaA(volproj), then overwritten by megaB(gather).
    short* wp   = (short*)out1;

    // ws layout: zeroed-by-init region first (cnt, nocc, invmap), then
    // compactM (zeroed by k_count's extra blocks), then the rest.
    char* w = (char*)d_ws;
    float* cnt       = (float*)w;                 w += (size_t)BT * NVOX * 4;       // 800000
    int*   nocc      = (int*)w;                   w += 256;
    int*   invmap    = (int*)w;                   w += (size_t)BT * NVOX * 4;       // 800000
    size_t z1 = (size_t)BT * NVOX * 4 + 256 + (size_t)BT * NVOX * 4;  // 1,600,256
    float* compactM  = (float*)w;                 w += (size_t)MAXS * CG * 4;       // 6488064
    int*   ptvox     = (int*)w;                   w += (size_t)NPTS * 4;            // 135168
    int*   list      = (int*)w;                   w += (size_t)MAXS * 4;            // 135168
    unsigned short* compact256h = (unsigned short*)w;  w += (size_t)MAXS * CO * 2;  // 17301504
    unsigned short* P = (unsigned short*)w;       // BT*NVOX*CG*2 = 19200000

    int cmz16 = (int)((size_t)MAXS * CG * 4 / 16);       // 405504 v4f elements
    int nbz   = (cmz16 + 255) / 256;                     // 1584 zero blocks

    k_init<<<201, 256, 0, stream>>>((v4f*)d_ws, (int)(z1 / 16), Wo2g, wp);
    k_count<<<NB_CT + nbz, 256, 0, stream>>>(centers, cnt, nocc, invmap, ptvox,
                                             list, (v4f*)compactM, cmz16);
    k_megaA<<<NB_VP + NB_SC, 256, 0, stream>>>(occ, wp, P, feats, ptvox, invmap, compactM);
    k_gemm<<<(MAXS + 31) / 32, 256, 0, stream>>>(compactM, cnt, list, nocc, Wg2o, bg2o, compact256h);
    k_megaB<<<NB_WR + NB_GA, 256, 0, stream>>>(invmap, compact256h, out0, centers, P, bo2g, out1);
}